// Round 1
// baseline (6849.379 us; speedup 1.0000x reference)
//
#include <hip/hip_runtime.h>
#include <hip/hip_bf16.h>
#include <cmath>

// Problem dims (fixed by reference)
#define B_  4
#define T_  4096
#define D_  1024
#define N_  64
#define H_  8
#define HD_ 128
#define BT_ (B_*T_)      // 16384
#define D2_ 2048

// ---------------------------------------------------------------------------
// Generic fp32 GEMM: C[M,N] = act( A'[M,K] @ W[N,K]^T + bias[N] ) (+ res)
// A' = LN(A) per-row if LN (using mu/rstd + gamma/beta over K)
// 128x128 tile, BK=16, 256 threads, 8x8 per thread.
// Requires M%128==0, N%128==0, K%16==0 (true for all uses here).
// ---------------------------------------------------------------------------
template<bool LN, bool GELU, bool RES>
__global__ __launch_bounds__(256) void gemm_kernel(
    const float* __restrict__ A, const float* __restrict__ W,
    const float* __restrict__ bias, const float* __restrict__ res,
    float* __restrict__ C, int M, int N, int K,
    const float* __restrict__ mu, const float* __restrict__ rstd,
    const float* __restrict__ gamma, const float* __restrict__ beta)
{
    const int BM = 128, BN = 128, BK = 16;
    __shared__ float As[BK][BM];
    __shared__ float Ws[BK][BN];

    const int n0 = blockIdx.x * BN;
    const int m0 = blockIdx.y * BM;
    const int tid = threadIdx.x;
    const int tx = tid & 15;        // 0..15 -> N
    const int ty = tid >> 4;        // 0..15 -> M

    const int lr = tid >> 2;        // 0..63 loader row
    const int lc = (tid & 3) * 4;   // 0,4,8,12 loader col (float4)

    float acc[8][8] = {};

    for (int k0 = 0; k0 < K; k0 += BK) {
#pragma unroll
        for (int rr = 0; rr < 2; ++rr) {
            const int row = lr + rr * 64;
            // A tile (optionally LayerNorm'd on the fly)
            float4 av = *(const float4*)&A[(size_t)(m0 + row) * K + k0 + lc];
            if (LN) {
                const float mm = mu[m0 + row];
                const float rr_ = rstd[m0 + row];
                const float4 g = *(const float4*)&gamma[k0 + lc];
                const float4 be = *(const float4*)&beta[k0 + lc];
                av.x = (av.x - mm) * rr_ * g.x + be.x;
                av.y = (av.y - mm) * rr_ * g.y + be.y;
                av.z = (av.z - mm) * rr_ * g.z + be.z;
                av.w = (av.w - mm) * rr_ * g.w + be.w;
            }
            As[lc + 0][row] = av.x;
            As[lc + 1][row] = av.y;
            As[lc + 2][row] = av.z;
            As[lc + 3][row] = av.w;
            // W tile
            const float4 wv = *(const float4*)&W[(size_t)(n0 + row) * K + k0 + lc];
            Ws[lc + 0][row] = wv.x;
            Ws[lc + 1][row] = wv.y;
            Ws[lc + 2][row] = wv.z;
            Ws[lc + 3][row] = wv.w;
        }
        __syncthreads();
#pragma unroll
        for (int kk = 0; kk < BK; ++kk) {
            float a[8], b[8];
            *(float4*)&a[0] = *(const float4*)&As[kk][ty * 8];
            *(float4*)&a[4] = *(const float4*)&As[kk][ty * 8 + 4];
            *(float4*)&b[0] = *(const float4*)&Ws[kk][tx * 8];
            *(float4*)&b[4] = *(const float4*)&Ws[kk][tx * 8 + 4];
#pragma unroll
            for (int i = 0; i < 8; ++i)
#pragma unroll
                for (int j = 0; j < 8; ++j)
                    acc[i][j] += a[i] * b[j];
        }
        __syncthreads();
    }

    // epilogue
#pragma unroll
    for (int i = 0; i < 8; ++i) {
        const int m = m0 + ty * 8 + i;
        const size_t rowbase = (size_t)m * N + n0 + tx * 8;
#pragma unroll
        for (int jj = 0; jj < 2; ++jj) {
            const int nb = n0 + tx * 8 + jj * 4;
            const float4 b4 = *(const float4*)&bias[nb];
            float4 v;
            v.x = acc[i][jj * 4 + 0] + b4.x;
            v.y = acc[i][jj * 4 + 1] + b4.y;
            v.z = acc[i][jj * 4 + 2] + b4.z;
            v.w = acc[i][jj * 4 + 3] + b4.w;
            if (GELU) {
                v.x = 0.5f * v.x * (1.0f + erff(v.x * 0.70710678118654752f));
                v.y = 0.5f * v.y * (1.0f + erff(v.y * 0.70710678118654752f));
                v.z = 0.5f * v.z * (1.0f + erff(v.z * 0.70710678118654752f));
                v.w = 0.5f * v.w * (1.0f + erff(v.w * 0.70710678118654752f));
            }
            if (RES) {
                const float4 r4 = *(const float4*)&res[rowbase + jj * 4];
                v.x += r4.x; v.y += r4.y; v.z += r4.z; v.w += r4.w;
            }
            *(float4*)&C[rowbase + jj * 4] = v;
        }
    }
}

// ---------------------------------------------------------------------------
// LayerNorm stats: one block (256 thr) per row of 1024.
// ---------------------------------------------------------------------------
__global__ __launch_bounds__(256) void ln_stats_kernel(
    const float* __restrict__ x, float* __restrict__ mu, float* __restrict__ rstd)
{
    const int m = blockIdx.x;
    const float4 v = ((const float4*)(x + (size_t)m * D_))[threadIdx.x];
    float s = v.x + v.y + v.z + v.w;
    float ss = v.x * v.x + v.y * v.y + v.z * v.z + v.w * v.w;
#pragma unroll
    for (int off = 32; off; off >>= 1) {
        s += __shfl_xor(s, off);
        ss += __shfl_xor(ss, off);
    }
    __shared__ float bs[4], bss[4];
    const int wave = threadIdx.x >> 6;
    if ((threadIdx.x & 63) == 0) { bs[wave] = s; bss[wave] = ss; }
    __syncthreads();
    if (threadIdx.x == 0) {
        const float S = bs[0] + bs[1] + bs[2] + bs[3];
        const float SS = bss[0] + bss[1] + bss[2] + bss[3];
        const float mean = S * (1.0f / D_);
        const float var = SS * (1.0f / D_) - mean * mean;
        mu[m] = mean;
        rstd[m] = rsqrtf(var + 1e-5f);
    }
}

// ---------------------------------------------------------------------------
// Fused attention for one (b,h) over a tile of 128 t-rows.
// q (B,T,D) is overwritten in-place with ctx. K staged in LDS (pad 129),
// V read via L1 (32KB/head). Softmax in-wave (lane n = key n).
// Accumulates S[b][n] = mean over (h,t) of attn for top-k.
// ---------------------------------------------------------------------------
__global__ __launch_bounds__(256) void attn_kernel(
    float* __restrict__ q, const float* __restrict__ kbuf,
    const float* __restrict__ vbuf, float* __restrict__ S)
{
    const int bh = blockIdx.x;
    const int b = bh / H_, hh = bh % H_;
    const int t0 = blockIdx.y * 128;

    __shared__ float Kl[N_ * 129];
    __shared__ float ql[4 * HD_];
    __shared__ float pl[4 * N_];

    const int tid = threadIdx.x;
    for (int idx = tid; idx < N_ * HD_; idx += 256) {
        const int n = idx >> 7, j = idx & 127;
        Kl[n * 129 + j] = kbuf[((size_t)(b * N_ + n)) * D_ + hh * HD_ + j];
    }
    __syncthreads();

    const int wave = tid >> 6, lane = tid & 63;
    const float scale = 0.088388347648318441f;  // 1/sqrt(128)
    float accS = 0.0f;
    const float* vb = vbuf + ((size_t)(b * N_)) * D_ + hh * HD_;

    for (int r = wave; r < 128; r += 4) {
        const int t = t0 + r;
        const size_t qoff = ((size_t)(b * T_ + t)) * D_ + hh * HD_;
        ql[wave * HD_ + lane] = q[qoff + lane];
        ql[wave * HD_ + 64 + lane] = q[qoff + 64 + lane];
        asm volatile("s_waitcnt lgkmcnt(0)" ::: "memory");

        float s = 0.0f;
#pragma unroll 8
        for (int j = 0; j < HD_; ++j)
            s += ql[wave * HD_ + j] * Kl[lane * 129 + j];
        s *= scale;

        float m = s;
#pragma unroll
        for (int off = 32; off; off >>= 1) m = fmaxf(m, __shfl_xor(m, off));
        float p = __expf(s - m);
        float sum = p;
#pragma unroll
        for (int off = 32; off; off >>= 1) sum += __shfl_xor(sum, off);
        p /= sum;
        accS += p;

        pl[wave * N_ + lane] = p;
        asm volatile("s_waitcnt lgkmcnt(0)" ::: "memory");

        float c0 = 0.0f, c1 = 0.0f;
#pragma unroll 8
        for (int n = 0; n < N_; ++n) {
            const float pn = pl[wave * N_ + n];
            c0 += pn * vb[(size_t)n * D_ + lane];
            c1 += pn * vb[(size_t)n * D_ + 64 + lane];
        }
        q[qoff + lane] = c0;
        q[qoff + 64 + lane] = c1;
    }
    atomicAdd(&S[b * N_ + lane], accS * (1.0f / (H_ * (float)T_)));
}

// ---------------------------------------------------------------------------
// frame_summary: mean over T. grid (B, D/256, T/512), atomicAdd partials.
// ---------------------------------------------------------------------------
__global__ __launch_bounds__(256) void frame_summary_kernel(
    const float* __restrict__ cf, float* __restrict__ fs)
{
    const int b = blockIdx.x;
    const int d = blockIdx.y * 256 + threadIdx.x;
    const int t0 = blockIdx.z * 512;
    float s = 0.0f;
    for (int t = t0; t < t0 + 512; ++t)
        s += cf[((size_t)(b * T_ + t)) * D_ + d];
    atomicAdd(&fs[b * D_ + d], s * (1.0f / (float)T_));
}

__global__ __launch_bounds__(256) void mem_summary_kernel(
    const float* __restrict__ em, float* __restrict__ ms)
{
    const int b = blockIdx.x;
    const int d = blockIdx.y * 256 + threadIdx.x;
    float s = 0.0f;
#pragma unroll 4
    for (int n = 0; n < N_; ++n)
        s += em[((size_t)(b * N_ + n)) * D_ + d];
    ms[b * D_ + d] = s * (1.0f / (float)N_);
}

// gate = sigmoid([fs,ms] @ gw^T + gb); nm = gate*fs + (1-gate)*ms
__global__ __launch_bounds__(256) void gate_kernel(
    const float* __restrict__ fs, const float* __restrict__ ms,
    const float* __restrict__ gw, const float* __restrict__ gb,
    float* __restrict__ nm)
{
    const int b = blockIdx.x;
    const int d = blockIdx.y * 256 + threadIdx.x;
    const float* wrow = gw + (size_t)d * D2_;
    const float* f = fs + b * D_;
    const float* mm = ms + b * D_;
    float g = gb[d];
    for (int j = 0; j < D_; ++j) g += f[j] * wrow[j];
    for (int j = 0; j < D_; ++j) g += mm[j] * wrow[D_ + j];
    const float sig = 1.0f / (1.0f + __expf(-g));
    nm[b * D_ + d] = sig * f[d] + (1.0f - sig) * mm[d];
}

// top-3 of S[b][:] (lower index wins ties, matching lax.top_k), then
// em_out = em with those rows blended 0.7*old + 0.3*nm.
__global__ __launch_bounds__(256) void topk_update_kernel(
    const float* __restrict__ S, const float* __restrict__ em,
    const float* __restrict__ nm, float* __restrict__ emo)
{
    const int b = blockIdx.x;
    __shared__ int topi[3];
    const int tid = threadIdx.x;
    if (tid < 64) {
        float sv = S[b * N_ + tid];
#pragma unroll
        for (int k = 0; k < 3; ++k) {
            float v = sv;
            int idx = tid;
#pragma unroll
            for (int off = 32; off; off >>= 1) {
                const float ov = __shfl_xor(v, off);
                const int oi = __shfl_xor(idx, off);
                if (ov > v || (ov == v && oi < idx)) { v = ov; idx = oi; }
            }
            if (tid == 0) topi[k] = idx;
            if (tid == idx) sv = -INFINITY;
        }
    }
    __syncthreads();
    const int i0 = topi[0], i1 = topi[1], i2 = topi[2];
    const float4* emb = (const float4*)(em + (size_t)b * N_ * D_);
    const float4* nmb = (const float4*)(nm + (size_t)b * D_);
    float4* outb = (float4*)(emo + (size_t)b * N_ * D_);
    for (int idx = tid; idx < N_ * D_ / 4; idx += 256) {
        const int n = idx >> 8;       // idx / 256  (256 float4 per row)
        const int d4 = idx & 255;
        float4 v = emb[idx];
        if (n == i0 || n == i1 || n == i2) {
            const float4 nv = nmb[d4];
            v.x = 0.7f * v.x + 0.3f * nv.x;
            v.y = 0.7f * v.y + 0.3f * nv.y;
            v.z = 0.7f * v.z + 0.3f * nv.z;
            v.w = 0.7f * v.w + 0.3f * nv.w;
        }
        outb[idx] = v;
    }
}

// ---------------------------------------------------------------------------
extern "C" void kernel_launch(void* const* d_in, const int* in_sizes, int n_in,
                              void* d_out, int out_size, void* d_ws, size_t ws_size,
                              hipStream_t stream)
{
    const float* cf  = (const float*)d_in[0];
    const float* em  = (const float*)d_in[1];
    const float* ipw = (const float*)d_in[2];
    const float* ipb = (const float*)d_in[3];
    const float* opw = (const float*)d_in[4];
    const float* opb = (const float*)d_in[5];
    const float* lng = (const float*)d_in[6];
    const float* lnb = (const float*)d_in[7];
    const float* w1  = (const float*)d_in[8];
    const float* b1  = (const float*)d_in[9];
    const float* w2  = (const float*)d_in[10];
    const float* b2  = (const float*)d_in[11];
    const float* gw  = (const float*)d_in[12];
    const float* gb  = (const float*)d_in[13];

    float* x   = (float*)d_out;                  // (B,T,D)
    float* emo = x + (size_t)BT_ * D_;           // (B,N,D)

    // workspace layout (floats). q and h alias (q dead after out-proj).
    float* Abuf = (float*)d_ws;
    float* q  = Abuf;                            // 16,777,216 (within 33,554,432 region)
    float* h  = Abuf;                            // 33,554,432
    float* kb = Abuf + 33554432;                 // 262,144
    float* vb = kb + 262144;                     // 262,144
    float* mu = vb + 262144;                     // 16,384
    float* rs = mu + 16384;                      // 16,384
    float* S  = rs + 16384;                      // 256
    float* fs = S + 256;                         // 4,096
    float* ms = fs + 4096;                       // 4,096
    float* nm = ms + 4096;                       // 4,096

    hipMemsetAsync(S, 0, (256 + 4096) * sizeof(float), stream);  // S + fs

    const dim3 blk(256);

    // q = cf @ wq^T + bq
    gemm_kernel<false, false, false><<<dim3(8, 128), blk, 0, stream>>>(
        cf, ipw, ipb, nullptr, q, BT_, D_, D_, nullptr, nullptr, nullptr, nullptr);
    // k = em @ wk^T + bk ; v = em @ wv^T + bv
    gemm_kernel<false, false, false><<<dim3(8, 2), blk, 0, stream>>>(
        em, ipw + 1048576, ipb + 1024, nullptr, kb, B_ * N_, D_, D_, nullptr, nullptr, nullptr, nullptr);
    gemm_kernel<false, false, false><<<dim3(8, 2), blk, 0, stream>>>(
        em, ipw + 2097152, ipb + 2048, nullptr, vb, B_ * N_, D_, D_, nullptr, nullptr, nullptr, nullptr);

    // attention (q -> ctx in place, accumulate S)
    attn_kernel<<<dim3(B_ * H_, T_ / 128), blk, 0, stream>>>(q, kb, vb, S);

    // x = ctx @ out_proj^T + out_proj_b + cf
    gemm_kernel<false, false, true><<<dim3(8, 128), blk, 0, stream>>>(
        q, opw, opb, cf, x, BT_, D_, D_, nullptr, nullptr, nullptr, nullptr);

    // 3 FFN layers
    for (int i = 0; i < 3; ++i) {
        ln_stats_kernel<<<BT_, 256, 0, stream>>>(x, mu, rs);
        gemm_kernel<true, true, false><<<dim3(16, 128), blk, 0, stream>>>(
            x, w1 + (size_t)i * 2097152, b1 + i * 2048, nullptr, h,
            BT_, D2_, D_, mu, rs, lng + i * 1024, lnb + i * 1024);
        gemm_kernel<false, false, true><<<dim3(8, 128), blk, 0, stream>>>(
            h, w2 + (size_t)i * 2097152, b2 + i * 1024, x, x,
            BT_, D_, D2_, nullptr, nullptr, nullptr, nullptr);
    }

    // summaries + gate + top-k memory update
    frame_summary_kernel<<<dim3(B_, 4, 8), blk, 0, stream>>>(cf, fs);
    mem_summary_kernel<<<dim3(B_, 4), blk, 0, stream>>>(em, ms);
    gate_kernel<<<dim3(B_, 4), blk, 0, stream>>>(fs, ms, gw, gb, nm);
    topk_update_kernel<<<B_, 256, 0, stream>>>(S, em, nm, emo);
}

// Round 2
// 1754.154 us; speedup vs baseline: 3.9047x; 3.9047x over previous
//
#include <hip/hip_runtime.h>
#include <hip/hip_bf16.h>
#include <cmath>

// Problem dims (fixed by reference)
#define B_  4
#define T_  4096
#define D_  1024
#define N_  64
#define H_  8
#define HD_ 128
#define BT_ (B_*T_)      // 16384
#define D2_ 2048

typedef __attribute__((ext_vector_type(8))) short bfrag8;   // 8 x bf16 (4 VGPRs)
typedef __attribute__((ext_vector_type(4))) float f32x4;

__device__ __forceinline__ void gload_lds16(const void* g, void* l) {
    __builtin_amdgcn_global_load_lds(
        (const __attribute__((address_space(1))) unsigned int*)g,
        (__attribute__((address_space(3))) unsigned int*)l,
        16, 0, 0);
}

// ---------------------------------------------------------------------------
// bf16 MFMA GEMM (m97 structure): C[M,N] = act(A[M,K] @ W[N,K]^T + bias) (+res)
// A, W bf16; bias/res fp32; C fp32 or bf16. 128x128 tile, BK=32, 256 thr,
// 4 waves in 2x2, each 64x64 via 4x4 mfma_f32_16x16x32_bf16 fragments.
// Requires M%128==0, N%128==0, K%32==0.
// ---------------------------------------------------------------------------
template<bool GELU, bool RES, bool OUTBF16>
__global__ __launch_bounds__(256) void gemm_bf16_kernel(
    const __hip_bfloat16* __restrict__ A, const __hip_bfloat16* __restrict__ Wt,
    const float* __restrict__ bias, const float* __restrict__ res,
    void* __restrict__ Cout, int M, int N, int K)
{
    __shared__ short As[128 * 32];
    __shared__ short Bs[128 * 32];

    const int tid = threadIdx.x;
    const int lane = tid & 63;
    const int wid = tid >> 6;
    const int wr = wid >> 1, wc = wid & 1;     // wave -> 64x64 quadrant
    const int m0 = blockIdx.y * 128;
    const int n0 = blockIdx.x * 128;

    const int srow = tid >> 2;                  // 0..63 staging row
    const int scol = (tid & 3) * 8;             // 0,8,16,24 staging col
    const short* Ag = (const short*)A;
    const short* Bg = (const short*)Wt;

    const int frow = lane & 15;                 // fragment row/col within 16
    const int fk   = (lane >> 4) * 8;           // fragment k-offset

    f32x4 acc[4][4] = {};

    for (int k0 = 0; k0 < K; k0 += 32) {
        __syncthreads();   // prev compute done reading LDS
        gload_lds16(Ag + (size_t)(m0 + srow) * K + k0 + scol,       &As[tid * 8]);
        gload_lds16(Ag + (size_t)(m0 + 64 + srow) * K + k0 + scol,  &As[2048 + tid * 8]);
        gload_lds16(Bg + (size_t)(n0 + srow) * K + k0 + scol,       &Bs[tid * 8]);
        gload_lds16(Bg + (size_t)(n0 + 64 + srow) * K + k0 + scol,  &Bs[2048 + tid * 8]);
        __syncthreads();   // compiler drains vmcnt before barrier

        bfrag8 a[4], b[4];
#pragma unroll
        for (int i = 0; i < 4; ++i)
            a[i] = *(const bfrag8*)&As[(wr * 64 + i * 16 + frow) * 32 + fk];
#pragma unroll
        for (int j = 0; j < 4; ++j)
            b[j] = *(const bfrag8*)&Bs[(wc * 64 + j * 16 + frow) * 32 + fk];
#pragma unroll
        for (int i = 0; i < 4; ++i)
#pragma unroll
            for (int j = 0; j < 4; ++j)
                acc[i][j] = __builtin_amdgcn_mfma_f32_16x16x32_bf16(a[i], b[j], acc[i][j], 0, 0, 0);
    }

    // epilogue: C/D map col=lane&15, row=(lane>>4)*4+reg
#pragma unroll
    for (int i = 0; i < 4; ++i) {
        const int rbase = m0 + wr * 64 + i * 16 + (lane >> 4) * 4;
#pragma unroll
        for (int r = 0; r < 4; ++r) {
            const size_t rowoff = (size_t)(rbase + r) * N;
#pragma unroll
            for (int j = 0; j < 4; ++j) {
                const int col = n0 + wc * 64 + j * 16 + (lane & 15);
                float v = acc[i][j][r] + bias[col];
                if (GELU) v = 0.5f * v * (1.0f + erff(v * 0.70710678118654752f));
                if (RES)  v += res[rowoff + col];
                if (OUTBF16) ((__hip_bfloat16*)Cout)[rowoff + col] = __float2bfloat16(v);
                else         ((float*)Cout)[rowoff + col] = v;
            }
        }
    }
}

// ---------------------------------------------------------------------------
// fp32 GEMM (kept for the tiny K/V projections, M=256)
// ---------------------------------------------------------------------------
__global__ __launch_bounds__(256) void gemm_f32_kernel(
    const float* __restrict__ A, const float* __restrict__ W,
    const float* __restrict__ bias, float* __restrict__ C, int M, int N, int K)
{
    const int BK = 16;
    __shared__ float As[BK][128];
    __shared__ float Ws[BK][128];
    const int n0 = blockIdx.x * 128;
    const int m0 = blockIdx.y * 128;
    const int tid = threadIdx.x;
    const int tx = tid & 15, ty = tid >> 4;
    const int lr = tid >> 2, lc = (tid & 3) * 4;
    float acc[8][8] = {};
    for (int k0 = 0; k0 < K; k0 += BK) {
#pragma unroll
        for (int rr = 0; rr < 2; ++rr) {
            const int row = lr + rr * 64;
            const float4 av = *(const float4*)&A[(size_t)(m0 + row) * K + k0 + lc];
            As[lc + 0][row] = av.x; As[lc + 1][row] = av.y;
            As[lc + 2][row] = av.z; As[lc + 3][row] = av.w;
            const float4 wv = *(const float4*)&W[(size_t)(n0 + row) * K + k0 + lc];
            Ws[lc + 0][row] = wv.x; Ws[lc + 1][row] = wv.y;
            Ws[lc + 2][row] = wv.z; Ws[lc + 3][row] = wv.w;
        }
        __syncthreads();
#pragma unroll
        for (int kk = 0; kk < BK; ++kk) {
            float a[8], b[8];
            *(float4*)&a[0] = *(const float4*)&As[kk][ty * 8];
            *(float4*)&a[4] = *(const float4*)&As[kk][ty * 8 + 4];
            *(float4*)&b[0] = *(const float4*)&Ws[kk][tx * 8];
            *(float4*)&b[4] = *(const float4*)&Ws[kk][tx * 8 + 4];
#pragma unroll
            for (int i = 0; i < 8; ++i)
#pragma unroll
                for (int j = 0; j < 8; ++j)
                    acc[i][j] += a[i] * b[j];
        }
        __syncthreads();
    }
#pragma unroll
    for (int i = 0; i < 8; ++i) {
        const size_t rowbase = (size_t)(m0 + ty * 8 + i) * N + n0 + tx * 8;
#pragma unroll
        for (int jj = 0; jj < 2; ++jj) {
            const float4 b4 = *(const float4*)&bias[n0 + tx * 8 + jj * 4];
            float4 v;
            v.x = acc[i][jj * 4 + 0] + b4.x; v.y = acc[i][jj * 4 + 1] + b4.y;
            v.z = acc[i][jj * 4 + 2] + b4.z; v.w = acc[i][jj * 4 + 3] + b4.w;
            *(float4*)&C[rowbase + jj * 4] = v;
        }
    }
}

// ---------------------------------------------------------------------------
// fp32 -> bf16 conversion, 8 elems/thread
// ---------------------------------------------------------------------------
__global__ __launch_bounds__(256) void cvt_kernel(
    const float* __restrict__ in, __hip_bfloat16* __restrict__ out, int n)
{
    const int i = (blockIdx.x * 256 + threadIdx.x) * 8;
    if (i >= n) return;
    const float4 v0 = *(const float4*)&in[i];
    const float4 v1 = *(const float4*)&in[i + 4];
    __hip_bfloat16 o[8];
    o[0] = __float2bfloat16(v0.x); o[1] = __float2bfloat16(v0.y);
    o[2] = __float2bfloat16(v0.z); o[3] = __float2bfloat16(v0.w);
    o[4] = __float2bfloat16(v1.x); o[5] = __float2bfloat16(v1.y);
    o[6] = __float2bfloat16(v1.z); o[7] = __float2bfloat16(v1.w);
    *(uint4*)&out[i] = *(uint4*)o;
}

// ---------------------------------------------------------------------------
// Fused LayerNorm (stats + apply) -> bf16. One block per row of 1024.
// ---------------------------------------------------------------------------
__global__ __launch_bounds__(256) void ln_fused_kernel(
    const float* __restrict__ x, const float* __restrict__ g,
    const float* __restrict__ be, __hip_bfloat16* __restrict__ out)
{
    const int m = blockIdx.x;
    const int c = threadIdx.x * 4;
    const float4 v = *(const float4*)&x[(size_t)m * D_ + c];
    float s = v.x + v.y + v.z + v.w;
    float ss = v.x * v.x + v.y * v.y + v.z * v.z + v.w * v.w;
#pragma unroll
    for (int off = 32; off; off >>= 1) {
        s += __shfl_xor(s, off);
        ss += __shfl_xor(ss, off);
    }
    __shared__ float bs[4], bss[4];
    const int wave = threadIdx.x >> 6;
    if ((threadIdx.x & 63) == 0) { bs[wave] = s; bss[wave] = ss; }
    __syncthreads();
    const float S = bs[0] + bs[1] + bs[2] + bs[3];
    const float SS = bss[0] + bss[1] + bss[2] + bss[3];
    const float mean = S * (1.0f / D_);
    const float rstd = rsqrtf(SS * (1.0f / D_) - mean * mean + 1e-5f);
    const float4 gg = *(const float4*)&g[c];
    const float4 bb = *(const float4*)&be[c];
    __hip_bfloat16 o[4];
    o[0] = __float2bfloat16((v.x - mean) * rstd * gg.x + bb.x);
    o[1] = __float2bfloat16((v.y - mean) * rstd * gg.y + bb.y);
    o[2] = __float2bfloat16((v.z - mean) * rstd * gg.z + bb.z);
    o[3] = __float2bfloat16((v.w - mean) * rstd * gg.w + bb.w);
    *(uint2*)&out[(size_t)m * D_ + c] = *(uint2*)o;
}

// ---------------------------------------------------------------------------
// Fused attention for one (b,h), 128 t-rows per block. Reads q fp32,
// K staged in LDS (pad 129), V via L1. Writes ctx as bf16 into ctxb.
// Accumulates S[b][n] = mean over (h,t) of attn.
// ---------------------------------------------------------------------------
__global__ __launch_bounds__(256) void attn_kernel(
    const float* __restrict__ q, const float* __restrict__ kbuf,
    const float* __restrict__ vbuf, __hip_bfloat16* __restrict__ ctxb,
    float* __restrict__ S)
{
    const int bh = blockIdx.x;
    const int b = bh / H_, hh = bh % H_;
    const int t0 = blockIdx.y * 128;

    __shared__ float Kl[N_ * 129];
    __shared__ float ql[4 * HD_];
    __shared__ float pl[4 * N_];

    const int tid = threadIdx.x;
    for (int idx = tid; idx < N_ * HD_; idx += 256) {
        const int n = idx >> 7, j = idx & 127;
        Kl[n * 129 + j] = kbuf[((size_t)(b * N_ + n)) * D_ + hh * HD_ + j];
    }
    __syncthreads();

    const int wave = tid >> 6, lane = tid & 63;
    const float scale = 0.088388347648318441f;  // 1/sqrt(128)
    float accS = 0.0f;
    const float* vb = vbuf + ((size_t)(b * N_)) * D_ + hh * HD_;

    for (int r = wave; r < 128; r += 4) {
        const int t = t0 + r;
        const size_t qoff = ((size_t)(b * T_ + t)) * D_ + hh * HD_;
        ql[wave * HD_ + lane] = q[qoff + lane];
        ql[wave * HD_ + 64 + lane] = q[qoff + 64 + lane];
        asm volatile("s_waitcnt lgkmcnt(0)" ::: "memory");

        float s = 0.0f;
#pragma unroll 8
        for (int j = 0; j < HD_; ++j)
            s += ql[wave * HD_ + j] * Kl[lane * 129 + j];
        s *= scale;

        float m = s;
#pragma unroll
        for (int off = 32; off; off >>= 1) m = fmaxf(m, __shfl_xor(m, off));
        float p = __expf(s - m);
        float sum = p;
#pragma unroll
        for (int off = 32; off; off >>= 1) sum += __shfl_xor(sum, off);
        p /= sum;
        accS += p;

        pl[wave * N_ + lane] = p;
        asm volatile("s_waitcnt lgkmcnt(0)" ::: "memory");

        float c0 = 0.0f, c1 = 0.0f;
#pragma unroll 8
        for (int n = 0; n < N_; ++n) {
            const float pn = pl[wave * N_ + n];
            c0 += pn * vb[(size_t)n * D_ + lane];
            c1 += pn * vb[(size_t)n * D_ + 64 + lane];
        }
        ctxb[qoff + lane] = __float2bfloat16(c0);
        ctxb[qoff + 64 + lane] = __float2bfloat16(c1);
    }
    atomicAdd(&S[b * N_ + lane], accS * (1.0f / (H_ * (float)T_)));
}

// ---------------------------------------------------------------------------
__global__ __launch_bounds__(256) void frame_summary_kernel(
    const float* __restrict__ cf, float* __restrict__ fs)
{
    const int b = blockIdx.x;
    const int d = blockIdx.y * 256 + threadIdx.x;
    const int t0 = blockIdx.z * 512;
    float s = 0.0f;
    for (int t = t0; t < t0 + 512; ++t)
        s += cf[((size_t)(b * T_ + t)) * D_ + d];
    atomicAdd(&fs[b * D_ + d], s * (1.0f / (float)T_));
}

__global__ __launch_bounds__(256) void mem_summary_kernel(
    const float* __restrict__ em, float* __restrict__ ms)
{
    const int b = blockIdx.x;
    const int d = blockIdx.y * 256 + threadIdx.x;
    float s = 0.0f;
#pragma unroll 4
    for (int n = 0; n < N_; ++n)
        s += em[((size_t)(b * N_ + n)) * D_ + d];
    ms[b * D_ + d] = s * (1.0f / (float)N_);
}

__global__ __launch_bounds__(256) void gate_kernel(
    const float* __restrict__ fs, const float* __restrict__ ms,
    const float* __restrict__ gw, const float* __restrict__ gb,
    float* __restrict__ nm)
{
    const int b = blockIdx.x;
    const int d = blockIdx.y * 256 + threadIdx.x;
    const float* wrow = gw + (size_t)d * D2_;
    const float* f = fs + b * D_;
    const float* mm = ms + b * D_;
    float g = gb[d];
    for (int j = 0; j < D_; ++j) g += f[j] * wrow[j];
    for (int j = 0; j < D_; ++j) g += mm[j] * wrow[D_ + j];
    const float sig = 1.0f / (1.0f + __expf(-g));
    nm[b * D_ + d] = sig * f[d] + (1.0f - sig) * mm[d];
}

__global__ __launch_bounds__(256) void topk_update_kernel(
    const float* __restrict__ S, const float* __restrict__ em,
    const float* __restrict__ nm, float* __restrict__ emo)
{
    const int b = blockIdx.x;
    __shared__ int topi[3];
    const int tid = threadIdx.x;
    if (tid < 64) {
        float sv = S[b * N_ + tid];
#pragma unroll
        for (int k = 0; k < 3; ++k) {
            float v = sv;
            int idx = tid;
#pragma unroll
            for (int off = 32; off; off >>= 1) {
                const float ov = __shfl_xor(v, off);
                const int oi = __shfl_xor(idx, off);
                if (ov > v || (ov == v && oi < idx)) { v = ov; idx = oi; }
            }
            if (tid == 0) topi[k] = idx;
            if (tid == idx) sv = -INFINITY;
        }
    }
    __syncthreads();
    const int i0 = topi[0], i1 = topi[1], i2 = topi[2];
    const float4* emb = (const float4*)(em + (size_t)b * N_ * D_);
    const float4* nmb = (const float4*)(nm + (size_t)b * D_);
    float4* outb = (float4*)(emo + (size_t)b * N_ * D_);
    for (int idx = tid; idx < N_ * D_ / 4; idx += 256) {
        const int n = idx >> 8;
        const int d4 = idx & 255;
        float4 v = emb[idx];
        if (n == i0 || n == i1 || n == i2) {
            const float4 nv = nmb[d4];
            v.x = 0.7f * v.x + 0.3f * nv.x;
            v.y = 0.7f * v.y + 0.3f * nv.y;
            v.z = 0.7f * v.z + 0.3f * nv.z;
            v.w = 0.7f * v.w + 0.3f * nv.w;
        }
        outb[idx] = v;
    }
}

// ---------------------------------------------------------------------------
extern "C" void kernel_launch(void* const* d_in, const int* in_sizes, int n_in,
                              void* d_out, int out_size, void* d_ws, size_t ws_size,
                              hipStream_t stream)
{
    const float* cf  = (const float*)d_in[0];
    const float* em  = (const float*)d_in[1];
    const float* ipw = (const float*)d_in[2];
    const float* ipb = (const float*)d_in[3];
    const float* opw = (const float*)d_in[4];
    const float* opb = (const float*)d_in[5];
    const float* lng = (const float*)d_in[6];
    const float* lnb = (const float*)d_in[7];
    const float* w1  = (const float*)d_in[8];
    const float* b1  = (const float*)d_in[9];
    const float* w2  = (const float*)d_in[10];
    const float* b2  = (const float*)d_in[11];
    const float* gw  = (const float*)d_in[12];
    const float* gb  = (const float*)d_in[13];

    float* x   = (float*)d_out;                  // (B,T,D)
    float* emo = x + (size_t)BT_ * D_;           // (B,N,D)

    // workspace layout (bytes). q fp32 (64MB) aliases h bf16 (64MB).
    char* w = (char*)d_ws;
    float* q            = (float*)w;             // 16384x1024 fp32
    __hip_bfloat16* h   = (__hip_bfloat16*)w;    // 16384x2048 bf16 (aliases q)
    w += 67108864;
    __hip_bfloat16* actb = (__hip_bfloat16*)w; w += 33554432;  // 16384x1024 bf16
    __hip_bfloat16* wqb  = (__hip_bfloat16*)w; w += 2097152;   // 1024x1024
    __hip_bfloat16* opwb = (__hip_bfloat16*)w; w += 2097152;   // 1024x1024
    __hip_bfloat16* w1b  = (__hip_bfloat16*)w; w += 12582912;  // 3x2048x1024
    __hip_bfloat16* w2b  = (__hip_bfloat16*)w; w += 12582912;  // 3x1024x2048
    float* kb = (float*)w; w += 1048576;         // 4x64x1024
    float* vb = (float*)w; w += 1048576;
    float* S  = (float*)w; w += 1024;            // 256 floats
    float* fs = (float*)w; w += 16384;           // 4096
    float* ms = (float*)w; w += 16384;
    float* nm = (float*)w; w += 16384;

    hipMemsetAsync(S, 0, (256 + 4096) * sizeof(float), stream);  // S + fs

    const dim3 blk(256);

    // bf16 copies of activations + weights
    cvt_kernel<<<8192, blk, 0, stream>>>(cf, actb, BT_ * D_);
    cvt_kernel<<<512,  blk, 0, stream>>>(ipw, wqb, D_ * D_);
    cvt_kernel<<<512,  blk, 0, stream>>>(opw, opwb, D_ * D_);
    cvt_kernel<<<3072, blk, 0, stream>>>(w1, w1b, 3 * D2_ * D_);
    cvt_kernel<<<3072, blk, 0, stream>>>(w2, w2b, 3 * D_ * D2_);

    // k, v projections (tiny, fp32)
    gemm_f32_kernel<<<dim3(8, 2), blk, 0, stream>>>(
        em, ipw + D_ * D_, ipb + D_, kb, B_ * N_, D_, D_);
    gemm_f32_kernel<<<dim3(8, 2), blk, 0, stream>>>(
        em, ipw + 2 * D_ * D_, ipb + 2 * D_, vb, B_ * N_, D_, D_);

    // q = cf @ wq^T + bq   (bf16 MFMA, fp32 out)
    gemm_bf16_kernel<false, false, false><<<dim3(8, 128), blk, 0, stream>>>(
        actb, wqb, ipb, nullptr, q, BT_, D_, D_);

    // attention: ctx (bf16) -> actb, S accumulated
    attn_kernel<<<dim3(B_ * H_, T_ / 128), blk, 0, stream>>>(q, kb, vb, actb, S);

    // x = ctx @ out_proj^T + out_proj_b + cf
    gemm_bf16_kernel<false, true, false><<<dim3(8, 128), blk, 0, stream>>>(
        actb, opwb, opb, cf, x, BT_, D_, D_);

    // 3 FFN layers
    for (int i = 0; i < 3; ++i) {
        ln_fused_kernel<<<BT_, blk, 0, stream>>>(
            x, lng + i * D_, lnb + i * D_, actb);
        gemm_bf16_kernel<true, false, true><<<dim3(16, 128), blk, 0, stream>>>(
            actb, w1b + (size_t)i * D2_ * D_, b1 + i * D2_, nullptr, h,
            BT_, D2_, D_);
        gemm_bf16_kernel<false, true, false><<<dim3(8, 128), blk, 0, stream>>>(
            h, w2b + (size_t)i * D_ * D2_, b2 + i * D_, x, x,
            BT_, D_, D2_);
    }

    // summaries + gate + top-k memory update
    frame_summary_kernel<<<dim3(B_, 4, 8), blk, 0, stream>>>(cf, fs);
    mem_summary_kernel<<<dim3(B_, 4), blk, 0, stream>>>(em, ms);
    gate_kernel<<<dim3(B_, 4), blk, 0, stream>>>(fs, ms, gw, gb, nm);
    topk_update_kernel<<<B_, blk, 0, stream>>>(S, em, nm, emo);
}

// Round 3
// 1281.765 us; speedup vs baseline: 5.3437x; 1.3685x over previous
//
#include <hip/hip_runtime.h>
#include <hip/hip_bf16.h>
#include <cmath>

// Problem dims (fixed by reference)
#define B_  4
#define T_  4096
#define D_  1024
#define N_  64
#define H_  8
#define HD_ 128
#define BT_ (B_*T_)      // 16384
#define D2_ 2048

typedef __attribute__((ext_vector_type(8))) short bfrag8;   // 8 x bf16 (4 VGPRs)
typedef __attribute__((ext_vector_type(4))) float f32x4;

__device__ __forceinline__ void gload_lds16(const void* g, void* l) {
    __builtin_amdgcn_global_load_lds(
        (const __attribute__((address_space(1))) unsigned int*)g,
        (__attribute__((address_space(3))) unsigned int*)l,
        16, 0, 0);
}

// ---------------------------------------------------------------------------
// bf16 MFMA GEMM (m97 structure + T1 XCD swizzle):
// C[M,N] = act(A[M,K] @ W[N,K]^T + bias) (+res). Requires grid%8==0.
// ---------------------------------------------------------------------------
template<bool GELU, bool RES, bool OUTBF16>
__global__ __launch_bounds__(256) void gemm_bf16_kernel(
    const __hip_bfloat16* __restrict__ A, const __hip_bfloat16* __restrict__ Wt,
    const float* __restrict__ bias, const float* __restrict__ res,
    void* __restrict__ Cout, int M, int N, int K)
{
    __shared__ short As[128 * 32];
    __shared__ short Bs[128 * 32];

    const int tid = threadIdx.x;
    const int lane = tid & 63;
    const int wid = tid >> 6;
    const int wr = wid >> 1, wc = wid & 1;

    // T1: XCD-aware block swizzle (nwg % 8 == 0 for all our grids)
    const int nwg = gridDim.x * gridDim.y;
    int lin = blockIdx.y * gridDim.x + blockIdx.x;
    lin = (lin & 7) * (nwg >> 3) + (lin >> 3);
    const int by = lin / gridDim.x;
    const int bx = lin - by * gridDim.x;
    const int m0 = by * 128;
    const int n0 = bx * 128;

    const int srow = tid >> 2;
    const int scol = (tid & 3) * 8;
    const short* Ag = (const short*)A;
    const short* Bg = (const short*)Wt;

    const int frow = lane & 15;
    const int fk   = (lane >> 4) * 8;

    f32x4 acc[4][4] = {};

    for (int k0 = 0; k0 < K; k0 += 32) {
        __syncthreads();
        gload_lds16(Ag + (size_t)(m0 + srow) * K + k0 + scol,       &As[tid * 8]);
        gload_lds16(Ag + (size_t)(m0 + 64 + srow) * K + k0 + scol,  &As[2048 + tid * 8]);
        gload_lds16(Bg + (size_t)(n0 + srow) * K + k0 + scol,       &Bs[tid * 8]);
        gload_lds16(Bg + (size_t)(n0 + 64 + srow) * K + k0 + scol,  &Bs[2048 + tid * 8]);
        __syncthreads();

        bfrag8 a[4], b[4];
#pragma unroll
        for (int i = 0; i < 4; ++i)
            a[i] = *(const bfrag8*)&As[(wr * 64 + i * 16 + frow) * 32 + fk];
#pragma unroll
        for (int j = 0; j < 4; ++j)
            b[j] = *(const bfrag8*)&Bs[(wc * 64 + j * 16 + frow) * 32 + fk];
#pragma unroll
        for (int i = 0; i < 4; ++i)
#pragma unroll
            for (int j = 0; j < 4; ++j)
                acc[i][j] = __builtin_amdgcn_mfma_f32_16x16x32_bf16(a[i], b[j], acc[i][j], 0, 0, 0);
    }

#pragma unroll
    for (int i = 0; i < 4; ++i) {
        const int rbase = m0 + wr * 64 + i * 16 + (lane >> 4) * 4;
#pragma unroll
        for (int r = 0; r < 4; ++r) {
            const size_t rowoff = (size_t)(rbase + r) * N;
#pragma unroll
            for (int j = 0; j < 4; ++j) {
                const int col = n0 + wc * 64 + j * 16 + (lane & 15);
                float v = acc[i][j][r] + bias[col];
                if (GELU) v = 0.5f * v * (1.0f + erff(v * 0.70710678118654752f));
                if (RES)  v += res[rowoff + col];
                if (OUTBF16) ((__hip_bfloat16*)Cout)[rowoff + col] = __float2bfloat16(v);
                else         ((float*)Cout)[rowoff + col] = v;
            }
        }
    }
}

// ---------------------------------------------------------------------------
// fp32 -> bf16 conversion, 8 elems/thread
// ---------------------------------------------------------------------------
__global__ __launch_bounds__(256) void cvt_kernel(
    const float* __restrict__ in, __hip_bfloat16* __restrict__ out, int n)
{
    const int i = (blockIdx.x * 256 + threadIdx.x) * 8;
    if (i >= n) return;
    const float4 v0 = *(const float4*)&in[i];
    const float4 v1 = *(const float4*)&in[i + 4];
    __hip_bfloat16 o[8];
    o[0] = __float2bfloat16(v0.x); o[1] = __float2bfloat16(v0.y);
    o[2] = __float2bfloat16(v0.z); o[3] = __float2bfloat16(v0.w);
    o[4] = __float2bfloat16(v1.x); o[5] = __float2bfloat16(v1.y);
    o[6] = __float2bfloat16(v1.z); o[7] = __float2bfloat16(v1.w);
    *(uint4*)&out[i] = *(uint4*)o;
}

// ---------------------------------------------------------------------------
// Fused LayerNorm (stats + apply) -> bf16. One block per row of 1024.
// ---------------------------------------------------------------------------
__global__ __launch_bounds__(256) void ln_fused_kernel(
    const float* __restrict__ x, const float* __restrict__ g,
    const float* __restrict__ be, __hip_bfloat16* __restrict__ out)
{
    const int m = blockIdx.x;
    const int c = threadIdx.x * 4;
    const float4 v = *(const float4*)&x[(size_t)m * D_ + c];
    float s = v.x + v.y + v.z + v.w;
    float ss = v.x * v.x + v.y * v.y + v.z * v.z + v.w * v.w;
#pragma unroll
    for (int off = 32; off; off >>= 1) {
        s += __shfl_xor(s, off);
        ss += __shfl_xor(ss, off);
    }
    __shared__ float bs[4], bss[4];
    const int wave = threadIdx.x >> 6;
    if ((threadIdx.x & 63) == 0) { bs[wave] = s; bss[wave] = ss; }
    __syncthreads();
    const float S = bs[0] + bs[1] + bs[2] + bs[3];
    const float SS = bss[0] + bss[1] + bss[2] + bss[3];
    const float mean = S * (1.0f / D_);
    const float rstd = rsqrtf(SS * (1.0f / D_) - mean * mean + 1e-5f);
    const float4 gg = *(const float4*)&g[c];
    const float4 bb = *(const float4*)&be[c];
    __hip_bfloat16 o[4];
    o[0] = __float2bfloat16((v.x - mean) * rstd * gg.x + bb.x);
    o[1] = __float2bfloat16((v.y - mean) * rstd * gg.y + bb.y);
    o[2] = __float2bfloat16((v.z - mean) * rstd * gg.z + bb.z);
    o[3] = __float2bfloat16((v.w - mean) * rstd * gg.w + bb.w);
    *(uint2*)&out[(size_t)m * D_ + c] = *(uint2*)o;
}

// ---------------------------------------------------------------------------
// V transpose: vtb[b,h,d,n] = vbb[b,n,h*128+d]  (bf16 -> bf16)
// ---------------------------------------------------------------------------
__global__ __launch_bounds__(256) void vtrans_kernel(
    const __hip_bfloat16* __restrict__ vbb, __hip_bfloat16* __restrict__ vtb)
{
    const int bh = blockIdx.x;
    const int b = bh >> 3, h = bh & 7;
    for (int ii = threadIdx.x; ii < HD_ * N_; ii += 256) {
        const int d = ii >> 6, n = ii & 63;
        vtb[(size_t)bh * (HD_ * N_) + ii] =
            vbb[(size_t)(b * N_ + n) * D_ + h * HD_ + d];
    }
}

// ---------------------------------------------------------------------------
// MFMA attention: one block = one (b,h) x 128 t-rows. N=64 keys fit fully.
// LDS tiles XOR-swizzled (slot8 ^= row&7) with pre-swizzled global sources.
// Writes ctx bf16 (coalesced via LDS), accumulates S[b][n].
// ---------------------------------------------------------------------------
__global__ __launch_bounds__(256) void attn_mfma_kernel(
    const __hip_bfloat16* __restrict__ qb, const __hip_bfloat16* __restrict__ kbb,
    const __hip_bfloat16* __restrict__ vtb, __hip_bfloat16* __restrict__ ctxb,
    float* __restrict__ S)
{
    const int bh = blockIdx.y;
    const int b = bh >> 3, hh = bh & 7;
    const int t0 = blockIdx.x * 128;

    __shared__ short Ql[128 * 128];          // reused as ctx staging later
    __shared__ short Kl[64 * 128];
    __shared__ short Vtl[128 * 64];
    __shared__ __hip_bfloat16 Pl[128 * 64];

    const int tid = threadIdx.x;
    const int lane = tid & 63;
    const int wid = tid >> 6;

    // ---- stage Q (32 KiB, 32 issues), K (16 KiB), Vt (16 KiB) ----
    const short* qg = (const short*)qb;
    for (int s = wid; s < 32; s += 4) {
        const int row = 4 * s + (lane >> 4);
        const int col8 = (lane & 15) ^ (row & 7);
        gload_lds16(qg + ((size_t)(b * T_ + t0 + row)) * D_ + hh * HD_ + col8 * 8,
                    &Ql[s * 512 + lane * 8]);
    }
    const short* kg = (const short*)kbb;
    for (int s = wid; s < 16; s += 4) {
        const int row = 4 * s + (lane >> 4);
        const int col8 = (lane & 15) ^ (row & 7);
        gload_lds16(kg + ((size_t)(b * N_ + row)) * D_ + hh * HD_ + col8 * 8,
                    &Kl[s * 512 + lane * 8]);
    }
    const short* vg = (const short*)vtb + (size_t)bh * (HD_ * N_);
    for (int s = wid; s < 16; s += 4) {
        const int row = 8 * s + (lane >> 3);
        const int col8 = (lane & 7) ^ (row & 7);
        gload_lds16(vg + row * 64 + col8 * 8, &Vtl[s * 512 + lane * 8]);
    }
    __syncthreads();

    const int frow = lane & 15;
    const int fk8  = lane >> 4;      // 0..3

    // ---- QK^T: per wave rows wid*32..+31, acc[2][4] over 64 key-cols ----
    f32x4 acc[2][4] = {};
#pragma unroll
    for (int ks = 0; ks < 4; ++ks) {
        bfrag8 a[2], bf[4];
#pragma unroll
        for (int i = 0; i < 2; ++i) {
            const int row = wid * 32 + i * 16 + frow;
            const int col8 = (ks * 4 + fk8) ^ (row & 7);
            a[i] = *(const bfrag8*)&Ql[row * 128 + col8 * 8];
        }
#pragma unroll
        for (int j = 0; j < 4; ++j) {
            const int row = j * 16 + frow;
            const int col8 = (ks * 4 + fk8) ^ (row & 7);
            bf[j] = *(const bfrag8*)&Kl[row * 128 + col8 * 8];
        }
#pragma unroll
        for (int i = 0; i < 2; ++i)
#pragma unroll
            for (int j = 0; j < 4; ++j)
                acc[i][j] = __builtin_amdgcn_mfma_f32_16x16x32_bf16(a[i], bf[j], acc[i][j], 0, 0, 0);
    }

    // ---- softmax over 64 cols (j regs x 16 lanes), write P to LDS bf16 ----
    const float scale = 0.088388347648318441f;   // 1/sqrt(128)
    float accS[4] = {0.f, 0.f, 0.f, 0.f};
#pragma unroll
    for (int i = 0; i < 2; ++i) {
#pragma unroll
        for (int r = 0; r < 4; ++r) {
            float sv[4];
            float m = -INFINITY;
#pragma unroll
            for (int j = 0; j < 4; ++j) { sv[j] = acc[i][j][r] * scale; m = fmaxf(m, sv[j]); }
#pragma unroll
            for (int off = 1; off < 16; off <<= 1) m = fmaxf(m, __shfl_xor(m, off));
            float sum = 0.f;
#pragma unroll
            for (int j = 0; j < 4; ++j) { sv[j] = __expf(sv[j] - m); sum += sv[j]; }
#pragma unroll
            for (int off = 1; off < 16; off <<= 1) sum += __shfl_xor(sum, off);
            const float inv = 1.0f / sum;
            const int row = wid * 32 + i * 16 + (lane >> 4) * 4 + r;
#pragma unroll
            for (int j = 0; j < 4; ++j) {
                const float pn = sv[j] * inv;
                accS[j] += pn;
                const int col = j * 16 + (lane & 15);
                Pl[row * 64 + (((col >> 3) ^ (row & 7)) << 3) + (col & 7)] = __float2bfloat16(pn);
            }
        }
    }
    // attn-mean accumulation for top-k
#pragma unroll
    for (int j = 0; j < 4; ++j) {
        float v = accS[j];
        v += __shfl_xor(v, 16);
        v += __shfl_xor(v, 32);
        if (lane < 16)
            atomicAdd(&S[b * N_ + j * 16 + lane], v * (1.0f / (H_ * (float)T_)));
    }
    __syncthreads();

    // ---- PV: ctx[128 x 128] = P[128 x 64] @ V[64 x 128] (Vt as W) ----
    f32x4 acc2[2][8] = {};
#pragma unroll
    for (int ks = 0; ks < 2; ++ks) {
        bfrag8 pa[2];
#pragma unroll
        for (int i = 0; i < 2; ++i) {
            const int row = wid * 32 + i * 16 + frow;
            const int col8 = (ks * 4 + fk8) ^ (row & 7);
            pa[i] = *(const bfrag8*)&Pl[row * 64 + col8 * 8];
        }
#pragma unroll
        for (int j = 0; j < 8; ++j) {
            const int row = j * 16 + frow;   // d index
            const int col8 = (ks * 4 + fk8) ^ (row & 7);
            const bfrag8 vv = *(const bfrag8*)&Vtl[row * 64 + col8 * 8];
#pragma unroll
            for (int i = 0; i < 2; ++i)
                acc2[i][j] = __builtin_amdgcn_mfma_f32_16x16x32_bf16(pa[i], vv, acc2[i][j], 0, 0, 0);
        }
    }

    // ---- ctx -> LDS (reuse Ql) -> coalesced bf16 global write ----
    short* Cl = Ql;
#pragma unroll
    for (int i = 0; i < 2; ++i)
#pragma unroll
        for (int r = 0; r < 4; ++r) {
            const int row = wid * 32 + i * 16 + (lane >> 4) * 4 + r;
#pragma unroll
            for (int j = 0; j < 8; ++j) {
                __hip_bfloat16 hv = __float2bfloat16(acc2[i][j][r]);
                Cl[row * 128 + j * 16 + (lane & 15)] = *(short*)&hv;
            }
        }
    __syncthreads();
    short* cg = (short*)ctxb;
#pragma unroll
    for (int s = 0; s < 8; ++s) {
        const int c = s * 256 + tid;        // 2048 chunks of 16B
        const int row = c >> 4;
        const int slot = c & 15;
        *(uint4*)&cg[((size_t)(b * T_ + t0 + row)) * D_ + hh * HD_ + slot * 8] =
            *(const uint4*)&Cl[row * 128 + slot * 8];
    }
}

// ---------------------------------------------------------------------------
__global__ __launch_bounds__(256) void frame_summary_kernel(
    const float* __restrict__ cf, float* __restrict__ fs)
{
    const int b = blockIdx.x;
    const int d = blockIdx.y * 256 + threadIdx.x;
    const int t0 = blockIdx.z * 512;
    float s = 0.0f;
    for (int t = t0; t < t0 + 512; ++t)
        s += cf[((size_t)(b * T_ + t)) * D_ + d];
    atomicAdd(&fs[b * D_ + d], s * (1.0f / (float)T_));
}

__global__ __launch_bounds__(256) void mem_summary_kernel(
    const float* __restrict__ em, float* __restrict__ ms)
{
    const int b = blockIdx.x;
    const int d = blockIdx.y * 256 + threadIdx.x;
    float s = 0.0f;
#pragma unroll 4
    for (int n = 0; n < N_; ++n)
        s += em[((size_t)(b * N_ + n)) * D_ + d];
    ms[b * D_ + d] = s * (1.0f / (float)N_);
}

__global__ __launch_bounds__(256) void gate_kernel(
    const float* __restrict__ fs, const float* __restrict__ ms,
    const float* __restrict__ gw, const float* __restrict__ gb,
    float* __restrict__ nm)
{
    const int b = blockIdx.x;
    const int d = blockIdx.y * 256 + threadIdx.x;
    const float* wrow = gw + (size_t)d * D2_;
    const float* f = fs + b * D_;
    const float* mm = ms + b * D_;
    float g = gb[d];
    for (int j = 0; j < D_; ++j) g += f[j] * wrow[j];
    for (int j = 0; j < D_; ++j) g += mm[j] * wrow[D_ + j];
    const float sig = 1.0f / (1.0f + __expf(-g));
    nm[b * D_ + d] = sig * f[d] + (1.0f - sig) * mm[d];
}

__global__ __launch_bounds__(256) void topk_update_kernel(
    const float* __restrict__ S, const float* __restrict__ em,
    const float* __restrict__ nm, float* __restrict__ emo)
{
    const int b = blockIdx.x;
    __shared__ int topi[3];
    const int tid = threadIdx.x;
    if (tid < 64) {
        float sv = S[b * N_ + tid];
#pragma unroll
        for (int k = 0; k < 3; ++k) {
            float v = sv;
            int idx = tid;
#pragma unroll
            for (int off = 32; off; off >>= 1) {
                const float ov = __shfl_xor(v, off);
                const int oi = __shfl_xor(idx, off);
                if (ov > v || (ov == v && oi < idx)) { v = ov; idx = oi; }
            }
            if (tid == 0) topi[k] = idx;
            if (tid == idx) sv = -INFINITY;
        }
    }
    __syncthreads();
    const int i0 = topi[0], i1 = topi[1], i2 = topi[2];
    const float4* emb = (const float4*)(em + (size_t)b * N_ * D_);
    const float4* nmb = (const float4*)(nm + (size_t)b * D_);
    float4* outb = (float4*)(emo + (size_t)b * N_ * D_);
    for (int idx = tid; idx < N_ * D_ / 4; idx += 256) {
        const int n = idx >> 8;
        const int d4 = idx & 255;
        float4 v = emb[idx];
        if (n == i0 || n == i1 || n == i2) {
            const float4 nv = nmb[d4];
            v.x = 0.7f * v.x + 0.3f * nv.x;
            v.y = 0.7f * v.y + 0.3f * nv.y;
            v.z = 0.7f * v.z + 0.3f * nv.z;
            v.w = 0.7f * v.w + 0.3f * nv.w;
        }
        outb[idx] = v;
    }
}

// ---------------------------------------------------------------------------
extern "C" void kernel_launch(void* const* d_in, const int* in_sizes, int n_in,
                              void* d_out, int out_size, void* d_ws, size_t ws_size,
                              hipStream_t stream)
{
    const float* cf  = (const float*)d_in[0];
    const float* em  = (const float*)d_in[1];
    const float* ipw = (const float*)d_in[2];
    const float* ipb = (const float*)d_in[3];
    const float* opw = (const float*)d_in[4];
    const float* opb = (const float*)d_in[5];
    const float* lng = (const float*)d_in[6];
    const float* lnb = (const float*)d_in[7];
    const float* w1  = (const float*)d_in[8];
    const float* b1  = (const float*)d_in[9];
    const float* w2  = (const float*)d_in[10];
    const float* b2  = (const float*)d_in[11];
    const float* gw  = (const float*)d_in[12];
    const float* gb  = (const float*)d_in[13];

    float* x   = (float*)d_out;                  // (B,T,D)
    float* emo = x + (size_t)BT_ * D_;           // (B,N,D)

    // workspace layout (bytes); qb aliases first half of h (q dead before FFN)
    char* w = (char*)d_ws;
    __hip_bfloat16* h    = (__hip_bfloat16*)w;   // 16384x2048 bf16 (64MB)
    __hip_bfloat16* qbuf = (__hip_bfloat16*)w;   // 16384x1024 bf16 (aliases h)
    w += 67108864;
    __hip_bfloat16* actb = (__hip_bfloat16*)w; w += 33554432;  // 16384x1024
    __hip_bfloat16* ipwb = (__hip_bfloat16*)w; w += 6291456;   // 3x1024x1024
    __hip_bfloat16* opwb = (__hip_bfloat16*)w; w += 2097152;   // 1024x1024
    __hip_bfloat16* w1b  = (__hip_bfloat16*)w; w += 12582912;  // 3x2048x1024
    __hip_bfloat16* w2b  = (__hip_bfloat16*)w; w += 12582912;  // 3x1024x2048
    __hip_bfloat16* emb  = (__hip_bfloat16*)w; w += 524288;    // 4x64x1024
    __hip_bfloat16* kbb  = (__hip_bfloat16*)w; w += 524288;
    __hip_bfloat16* vbb  = (__hip_bfloat16*)w; w += 524288;
    __hip_bfloat16* vtb  = (__hip_bfloat16*)w; w += 524288;    // [B,H,128,64]
    float* S  = (float*)w; w += 1024;            // 256 floats
    float* fs = (float*)w; w += 16384;           // 4096
    float* ms = (float*)w; w += 16384;
    float* nm = (float*)w; w += 16384;

    hipMemsetAsync(S, 0, (256 + 4096) * sizeof(float), stream);  // S + fs

    const dim3 blk(256);

    // bf16 copies
    cvt_kernel<<<8192, blk, 0, stream>>>(cf, actb, BT_ * D_);
    cvt_kernel<<<128,  blk, 0, stream>>>(em, emb, B_ * N_ * D_);
    cvt_kernel<<<1536, blk, 0, stream>>>(ipw, ipwb, 3 * D_ * D_);
    cvt_kernel<<<512,  blk, 0, stream>>>(opw, opwb, D_ * D_);
    cvt_kernel<<<3072, blk, 0, stream>>>(w1, w1b, 3 * D2_ * D_);
    cvt_kernel<<<3072, blk, 0, stream>>>(w2, w2b, 3 * D_ * D2_);

    // projections (all bf16 MFMA, bf16 out)
    gemm_bf16_kernel<false, false, true><<<dim3(8, 128), blk, 0, stream>>>(
        actb, ipwb, ipb, nullptr, qbuf, BT_, D_, D_);
    gemm_bf16_kernel<false, false, true><<<dim3(8, 2), blk, 0, stream>>>(
        emb, ipwb + D_ * D_, ipb + D_, nullptr, kbb, B_ * N_, D_, D_);
    gemm_bf16_kernel<false, false, true><<<dim3(8, 2), blk, 0, stream>>>(
        emb, ipwb + 2 * D_ * D_, ipb + 2 * D_, nullptr, vbb, B_ * N_, D_, D_);
    vtrans_kernel<<<B_ * H_, blk, 0, stream>>>(vbb, vtb);

    // attention: ctx (bf16) -> actb, S accumulated
    attn_mfma_kernel<<<dim3(T_ / 128, B_ * H_), blk, 0, stream>>>(
        qbuf, kbb, vtb, actb, S);

    // x = ctx @ out_proj^T + out_proj_b + cf
    gemm_bf16_kernel<false, true, false><<<dim3(8, 128), blk, 0, stream>>>(
        actb, opwb, opb, cf, x, BT_, D_, D_);

    // 3 FFN layers
    for (int i = 0; i < 3; ++i) {
        ln_fused_kernel<<<BT_, blk, 0, stream>>>(
            x, lng + i * D_, lnb + i * D_, actb);
        gemm_bf16_kernel<true, false, true><<<dim3(16, 128), blk, 0, stream>>>(
            actb, w1b + (size_t)i * D2_ * D_, b1 + i * D2_, nullptr, h,
            BT_, D2_, D_);
        gemm_bf16_kernel<false, true, false><<<dim3(8, 128), blk, 0, stream>>>(
            h, w2b + (size_t)i * D_ * D2_, b2 + i * D_, x, x,
            BT_, D_, D2_);
    }

    // summaries + gate + top-k memory update
    frame_summary_kernel<<<dim3(B_, 4, 8), blk, 0, stream>>>(cf, fs);
    mem_summary_kernel<<<dim3(B_, 4), blk, 0, stream>>>(em, ms);
    gate_kernel<<<dim3(B_, 4), blk, 0, stream>>>(fs, ms, gw, gb, nm);
    topk_update_kernel<<<B_, blk, 0, stream>>>(S, em, nm, emo);
}

// Round 4
// 1165.862 us; speedup vs baseline: 5.8749x; 1.0994x over previous
//
#include <hip/hip_runtime.h>
#include <hip/hip_bf16.h>
#include <cmath>

// Problem dims (fixed by reference)
#define B_  4
#define T_  4096
#define D_  1024
#define N_  64
#define H_  8
#define HD_ 128
#define BT_ (B_*T_)      // 16384
#define D2_ 2048

typedef __attribute__((ext_vector_type(8))) short bfrag8;   // 8 x bf16 (4 VGPRs)
typedef __attribute__((ext_vector_type(4))) float f32x4;

__device__ __forceinline__ void gload_lds16(const void* g, void* l) {
    __builtin_amdgcn_global_load_lds(
        (const __attribute__((address_space(1))) unsigned int*)g,
        (__attribute__((address_space(3))) unsigned int*)l,
        16, 0, 0);
}

// ---------------------------------------------------------------------------
// bf16 MFMA GEMM, 256x256 tile, BK=64, 512 thr (8 waves 2x4), double-buffered
// LDS (128 KiB) with T3 "minimum 2-phase" prefetch + T2 slot-XOR swizzle.
// C[M,N] = act(A[M,K] @ W[N,K]^T + bias) (+res).  M%256==0 (or M==256),
// N%256==0, K%64==0.
// ---------------------------------------------------------------------------
template<bool GELU, bool RES, bool OUTBF16>
__global__ __launch_bounds__(512, 2) void gemm_bf16_kernel(
    const __hip_bfloat16* __restrict__ A, const __hip_bfloat16* __restrict__ Wt,
    const float* __restrict__ bias, const float* __restrict__ res,
    void* __restrict__ Cout, int M, int N, int K)
{
    __shared__ short As[2 * 256 * 64];   // 64 KiB
    __shared__ short Bs[2 * 256 * 64];   // 64 KiB

    const int tid = threadIdx.x;
    const int lane = tid & 63;
    const int wid = tid >> 6;
    const int wr = wid >> 2;            // 0..1 -> 128-row half
    const int wc = wid & 3;             // 0..3 -> 64-col strip

    // T1: XCD-aware block swizzle (only when nwg % 8 == 0)
    const int nwg = gridDim.x * gridDim.y;
    int lin = blockIdx.y * gridDim.x + blockIdx.x;
    if ((nwg & 7) == 0) lin = (lin & 7) * (nwg >> 3) + (lin >> 3);
    const int by = lin / gridDim.x;
    const int bx = lin - by * gridDim.x;
    const int m0 = by * 256;
    const int n0 = bx * 256;

    const short* Ag = (const short*)A;
    const short* Bg = (const short*)Wt;

    const int frow = lane & 15;
    const int fk8  = lane >> 4;          // 0..3

    f32x4 acc[8][4] = {};

    const int nt = K >> 6;               // K-tiles of 64

    // stage K-tile t into buf[t&1]; LDS dest linear, global src inverse-swizzled
    auto STAGE = [&](int t) {
        const int kb = t << 6;
        short* Ab = &As[(t & 1) * 16384];
        short* Bb = &Bs[(t & 1) * 16384];
#pragma unroll
        for (int s = 0; s < 4; ++s) {
            const int L = s * 512 + tid;
            const int row = L >> 3, p = L & 7;
            const int g8 = ((p ^ (row & 7)) << 3);
            gload_lds16(Ag + (size_t)(m0 + row) * K + kb + g8, &Ab[L * 8]);
            gload_lds16(Bg + (size_t)(n0 + row) * K + kb + g8, &Bb[L * 8]);
        }
    };

    // prologue
    STAGE(0);
    asm volatile("s_waitcnt vmcnt(0)" ::: "memory");
    __syncthreads();

    for (int t = 0; t < nt; ++t) {
        if (t + 1 < nt) STAGE(t + 1);            // prefetch into other buffer
        const short* Ab = &As[(t & 1) * 16384];
        const short* Bb = &Bs[(t & 1) * 16384];
        for (int kk = 0; kk < 2; ++kk) {
            bfrag8 a[8], b[4];
#pragma unroll
            for (int i = 0; i < 8; ++i) {
                const int row = wr * 128 + i * 16 + frow;
                a[i] = *(const bfrag8*)&Ab[row * 64 + (((kk * 4 + fk8) ^ (row & 7)) << 3)];
            }
#pragma unroll
            for (int j = 0; j < 4; ++j) {
                const int row = wc * 64 + j * 16 + frow;
                b[j] = *(const bfrag8*)&Bb[row * 64 + (((kk * 4 + fk8) ^ (row & 7)) << 3)];
            }
#pragma unroll
            for (int i = 0; i < 8; ++i)
#pragma unroll
                for (int j = 0; j < 4; ++j)
                    acc[i][j] = __builtin_amdgcn_mfma_f32_16x16x32_bf16(a[i], b[j], acc[i][j], 0, 0, 0);
        }
        asm volatile("s_waitcnt vmcnt(0)" ::: "memory");  // next tile landed
        __syncthreads();                                   // all reads done
    }

    // epilogue: C/D map col=lane&15, row=(lane>>4)*4+reg
    float bias4[4];
#pragma unroll
    for (int j = 0; j < 4; ++j)
        bias4[j] = bias[n0 + wc * 64 + j * 16 + (lane & 15)];
#pragma unroll
    for (int i = 0; i < 8; ++i) {
        const int rbase = m0 + wr * 128 + i * 16 + (lane >> 4) * 4;
#pragma unroll
        for (int r = 0; r < 4; ++r) {
            const size_t rowoff = (size_t)(rbase + r) * N;
#pragma unroll
            for (int j = 0; j < 4; ++j) {
                const int col = n0 + wc * 64 + j * 16 + (lane & 15);
                float v = acc[i][j][r] + bias4[j];
                if (GELU) v = 0.5f * v * (1.0f + erff(v * 0.70710678118654752f));
                if (RES)  v += res[rowoff + col];
                if (OUTBF16) ((__hip_bfloat16*)Cout)[rowoff + col] = __float2bfloat16(v);
                else         ((float*)Cout)[rowoff + col] = v;
            }
        }
    }
}

// ---------------------------------------------------------------------------
// fp32 -> bf16 conversion, 8 elems/thread
// ---------------------------------------------------------------------------
__global__ __launch_bounds__(256) void cvt_kernel(
    const float* __restrict__ in, __hip_bfloat16* __restrict__ out, int n)
{
    const int i = (blockIdx.x * 256 + threadIdx.x) * 8;
    if (i >= n) return;
    const float4 v0 = *(const float4*)&in[i];
    const float4 v1 = *(const float4*)&in[i + 4];
    __hip_bfloat16 o[8];
    o[0] = __float2bfloat16(v0.x); o[1] = __float2bfloat16(v0.y);
    o[2] = __float2bfloat16(v0.z); o[3] = __float2bfloat16(v0.w);
    o[4] = __float2bfloat16(v1.x); o[5] = __float2bfloat16(v1.y);
    o[6] = __float2bfloat16(v1.z); o[7] = __float2bfloat16(v1.w);
    *(uint4*)&out[i] = *(uint4*)o;
}

// ---------------------------------------------------------------------------
// Fused LayerNorm (stats + apply) -> bf16. One block per row of 1024.
// ---------------------------------------------------------------------------
__global__ __launch_bounds__(256) void ln_fused_kernel(
    const float* __restrict__ x, const float* __restrict__ g,
    const float* __restrict__ be, __hip_bfloat16* __restrict__ out)
{
    const int m = blockIdx.x;
    const int c = threadIdx.x * 4;
    const float4 v = *(const float4*)&x[(size_t)m * D_ + c];
    float s = v.x + v.y + v.z + v.w;
    float ss = v.x * v.x + v.y * v.y + v.z * v.z + v.w * v.w;
#pragma unroll
    for (int off = 32; off; off >>= 1) {
        s += __shfl_xor(s, off);
        ss += __shfl_xor(ss, off);
    }
    __shared__ float bs[4], bss[4];
    const int wave = threadIdx.x >> 6;
    if ((threadIdx.x & 63) == 0) { bs[wave] = s; bss[wave] = ss; }
    __syncthreads();
    const float S = bs[0] + bs[1] + bs[2] + bs[3];
    const float SS = bss[0] + bss[1] + bss[2] + bss[3];
    const float mean = S * (1.0f / D_);
    const float rstd = rsqrtf(SS * (1.0f / D_) - mean * mean + 1e-5f);
    const float4 gg = *(const float4*)&g[c];
    const float4 bb = *(const float4*)&be[c];
    __hip_bfloat16 o[4];
    o[0] = __float2bfloat16((v.x - mean) * rstd * gg.x + bb.x);
    o[1] = __float2bfloat16((v.y - mean) * rstd * gg.y + bb.y);
    o[2] = __float2bfloat16((v.z - mean) * rstd * gg.z + bb.z);
    o[3] = __float2bfloat16((v.w - mean) * rstd * gg.w + bb.w);
    *(uint2*)&out[(size_t)m * D_ + c] = *(uint2*)o;
}

// ---------------------------------------------------------------------------
// V transpose: vtb[b,h,d,n] = vbb[b,n,h*128+d]  (bf16 -> bf16)
// ---------------------------------------------------------------------------
__global__ __launch_bounds__(256) void vtrans_kernel(
    const __hip_bfloat16* __restrict__ vbb, __hip_bfloat16* __restrict__ vtb)
{
    const int bh = blockIdx.x;
    const int b = bh >> 3, h = bh & 7;
    for (int ii = threadIdx.x; ii < HD_ * N_; ii += 256) {
        const int d = ii >> 6, n = ii & 63;
        vtb[(size_t)bh * (HD_ * N_) + ii] =
            vbb[(size_t)(b * N_ + n) * D_ + h * HD_ + d];
    }
}

// ---------------------------------------------------------------------------
// MFMA attention: one block = one (b,h) x 128 t-rows. N=64 keys fit fully.
// LDS tiles XOR-swizzled (slot8 ^= row&7) with pre-swizzled global sources.
// Writes ctx bf16 (coalesced via LDS), accumulates S[b][n].
// ---------------------------------------------------------------------------
__global__ __launch_bounds__(256) void attn_mfma_kernel(
    const __hip_bfloat16* __restrict__ qb, const __hip_bfloat16* __restrict__ kbb,
    const __hip_bfloat16* __restrict__ vtb, __hip_bfloat16* __restrict__ ctxb,
    float* __restrict__ S)
{
    const int bh = blockIdx.y;
    const int b = bh >> 3, hh = bh & 7;
    const int t0 = blockIdx.x * 128;

    __shared__ short Ql[128 * 128];          // reused as ctx staging later
    __shared__ short Kl[64 * 128];
    __shared__ short Vtl[128 * 64];
    __shared__ __hip_bfloat16 Pl[128 * 64];

    const int tid = threadIdx.x;
    const int lane = tid & 63;
    const int wid = tid >> 6;

    // ---- stage Q (32 KiB), K (16 KiB), Vt (16 KiB) ----
    const short* qg = (const short*)qb;
    for (int s = wid; s < 32; s += 4) {
        const int row = 4 * s + (lane >> 4);
        const int col8 = (lane & 15) ^ (row & 7);
        gload_lds16(qg + ((size_t)(b * T_ + t0 + row)) * D_ + hh * HD_ + col8 * 8,
                    &Ql[s * 512 + lane * 8]);
    }
    const short* kg = (const short*)kbb;
    for (int s = wid; s < 16; s += 4) {
        const int row = 4 * s + (lane >> 4);
        const int col8 = (lane & 15) ^ (row & 7);
        gload_lds16(kg + ((size_t)(b * N_ + row)) * D_ + hh * HD_ + col8 * 8,
                    &Kl[s * 512 + lane * 8]);
    }
    const short* vg = (const short*)vtb + (size_t)bh * (HD_ * N_);
    for (int s = wid; s < 16; s += 4) {
        const int row = 8 * s + (lane >> 3);
        const int col8 = (lane & 7) ^ (row & 7);
        gload_lds16(vg + row * 64 + col8 * 8, &Vtl[s * 512 + lane * 8]);
    }
    __syncthreads();

    const int frow = lane & 15;
    const int fk8  = lane >> 4;      // 0..3

    // ---- QK^T: per wave rows wid*32..+31, acc[2][4] over 64 key-cols ----
    f32x4 acc[2][4] = {};
#pragma unroll
    for (int ks = 0; ks < 4; ++ks) {
        bfrag8 a[2], bf[4];
#pragma unroll
        for (int i = 0; i < 2; ++i) {
            const int row = wid * 32 + i * 16 + frow;
            const int col8 = (ks * 4 + fk8) ^ (row & 7);
            a[i] = *(const bfrag8*)&Ql[row * 128 + col8 * 8];
        }
#pragma unroll
        for (int j = 0; j < 4; ++j) {
            const int row = j * 16 + frow;
            const int col8 = (ks * 4 + fk8) ^ (row & 7);
            bf[j] = *(const bfrag8*)&Kl[row * 128 + col8 * 8];
        }
#pragma unroll
        for (int i = 0; i < 2; ++i)
#pragma unroll
            for (int j = 0; j < 4; ++j)
                acc[i][j] = __builtin_amdgcn_mfma_f32_16x16x32_bf16(a[i], bf[j], acc[i][j], 0, 0, 0);
    }

    // ---- softmax over 64 cols, write P to LDS bf16 (swizzled) ----
    const float scale = 0.088388347648318441f;   // 1/sqrt(128)
    float accS[4] = {0.f, 0.f, 0.f, 0.f};
#pragma unroll
    for (int i = 0; i < 2; ++i) {
#pragma unroll
        for (int r = 0; r < 4; ++r) {
            float sv[4];
            float m = -INFINITY;
#pragma unroll
            for (int j = 0; j < 4; ++j) { sv[j] = acc[i][j][r] * scale; m = fmaxf(m, sv[j]); }
#pragma unroll
            for (int off = 1; off < 16; off <<= 1) m = fmaxf(m, __shfl_xor(m, off));
            float sum = 0.f;
#pragma unroll
            for (int j = 0; j < 4; ++j) { sv[j] = __expf(sv[j] - m); sum += sv[j]; }
#pragma unroll
            for (int off = 1; off < 16; off <<= 1) sum += __shfl_xor(sum, off);
            const float inv = 1.0f / sum;
            const int row = wid * 32 + i * 16 + (lane >> 4) * 4 + r;
#pragma unroll
            for (int j = 0; j < 4; ++j) {
                const float pn = sv[j] * inv;
                accS[j] += pn;
                const int col = j * 16 + (lane & 15);
                Pl[row * 64 + (((col >> 3) ^ (row & 7)) << 3) + (col & 7)] = __float2bfloat16(pn);
            }
        }
    }
    // attn-mean accumulation for top-k
#pragma unroll
    for (int j = 0; j < 4; ++j) {
        float v = accS[j];
        v += __shfl_xor(v, 16);
        v += __shfl_xor(v, 32);
        if (lane < 16)
            atomicAdd(&S[b * N_ + j * 16 + lane], v * (1.0f / (H_ * (float)T_)));
    }
    __syncthreads();

    // ---- PV: ctx[128 x 128] = P[128 x 64] @ V[64 x 128] (Vt as W) ----
    f32x4 acc2[2][8] = {};
#pragma unroll
    for (int ks = 0; ks < 2; ++ks) {
        bfrag8 pa[2];
#pragma unroll
        for (int i = 0; i < 2; ++i) {
            const int row = wid * 32 + i * 16 + frow;
            const int col8 = (ks * 4 + fk8) ^ (row & 7);
            pa[i] = *(const bfrag8*)&Pl[row * 64 + col8 * 8];
        }
#pragma unroll
        for (int j = 0; j < 8; ++j) {
            const int row = j * 16 + frow;   // d index
            const int col8 = (ks * 4 + fk8) ^ (row & 7);
            const bfrag8 vv = *(const bfrag8*)&Vtl[row * 64 + col8 * 8];
#pragma unroll
            for (int i = 0; i < 2; ++i)
                acc2[i][j] = __builtin_amdgcn_mfma_f32_16x16x32_bf16(pa[i], vv, acc2[i][j], 0, 0, 0);
        }
    }

    // ---- ctx -> LDS (reuse Ql) -> coalesced bf16 global write ----
    short* Cl = Ql;
#pragma unroll
    for (int i = 0; i < 2; ++i)
#pragma unroll
        for (int r = 0; r < 4; ++r) {
            const int row = wid * 32 + i * 16 + (lane >> 4) * 4 + r;
#pragma unroll
            for (int j = 0; j < 8; ++j) {
                __hip_bfloat16 hv = __float2bfloat16(acc2[i][j][r]);
                Cl[row * 128 + j * 16 + (lane & 15)] = *(short*)&hv;
            }
        }
    __syncthreads();
    short* cg = (short*)ctxb;
#pragma unroll
    for (int s = 0; s < 8; ++s) {
        const int c = s * 256 + tid;        // 2048 chunks of 16B
        const int row = c >> 4;
        const int slot = c & 15;
        *(uint4*)&cg[((size_t)(b * T_ + t0 + row)) * D_ + hh * HD_ + slot * 8] =
            *(const uint4*)&Cl[row * 128 + slot * 8];
    }
}

// ---------------------------------------------------------------------------
__global__ __launch_bounds__(256) void frame_summary_kernel(
    const float* __restrict__ cf, float* __restrict__ fs)
{
    const int b = blockIdx.x;
    const int d = blockIdx.y * 256 + threadIdx.x;
    const int t0 = blockIdx.z * 512;
    float s = 0.0f;
    for (int t = t0; t < t0 + 512; ++t)
        s += cf[((size_t)(b * T_ + t)) * D_ + d];
    atomicAdd(&fs[b * D_ + d], s * (1.0f / (float)T_));
}

__global__ __launch_bounds__(256) void mem_summary_kernel(
    const float* __restrict__ em, float* __restrict__ ms)
{
    const int b = blockIdx.x;
    const int d = blockIdx.y * 256 + threadIdx.x;
    float s = 0.0f;
#pragma unroll 4
    for (int n = 0; n < N_; ++n)
        s += em[((size_t)(b * N_ + n)) * D_ + d];
    ms[b * D_ + d] = s * (1.0f / (float)N_);
}

__global__ __launch_bounds__(256) void gate_kernel(
    const float* __restrict__ fs, const float* __restrict__ ms,
    const float* __restrict__ gw, const float* __restrict__ gb,
    float* __restrict__ nm)
{
    const int b = blockIdx.x;
    const int d = blockIdx.y * 256 + threadIdx.x;
    const float* wrow = gw + (size_t)d * D2_;
    const float* f = fs + b * D_;
    const float* mm = ms + b * D_;
    float g = gb[d];
    for (int j = 0; j < D_; ++j) g += f[j] * wrow[j];
    for (int j = 0; j < D_; ++j) g += mm[j] * wrow[D_ + j];
    const float sig = 1.0f / (1.0f + __expf(-g));
    nm[b * D_ + d] = sig * f[d] + (1.0f - sig) * mm[d];
}

__global__ __launch_bounds__(256) void topk_update_kernel(
    const float* __restrict__ S, const float* __restrict__ em,
    const float* __restrict__ nm, float* __restrict__ emo)
{
    const int b = blockIdx.x;
    __shared__ int topi[3];
    const int tid = threadIdx.x;
    if (tid < 64) {
        float sv = S[b * N_ + tid];
#pragma unroll
        for (int k = 0; k < 3; ++k) {
            float v = sv;
            int idx = tid;
#pragma unroll
            for (int off = 32; off; off >>= 1) {
                const float ov = __shfl_xor(v, off);
                const int oi = __shfl_xor(idx, off);
                if (ov > v || (ov == v && oi < idx)) { v = ov; idx = oi; }
            }
            if (tid == 0) topi[k] = idx;
            if (tid == idx) sv = -INFINITY;
        }
    }
    __syncthreads();
    const int i0 = topi[0], i1 = topi[1], i2 = topi[2];
    const float4* emb = (const float4*)(em + (size_t)b * N_ * D_);
    const float4* nmb = (const float4*)(nm + (size_t)b * D_);
    float4* outb = (float4*)(emo + (size_t)b * N_ * D_);
    for (int idx = tid; idx < N_ * D_ / 4; idx += 256) {
        const int n = idx >> 8;
        const int d4 = idx & 255;
        float4 v = emb[idx];
        if (n == i0 || n == i1 || n == i2) {
            const float4 nv = nmb[d4];
            v.x = 0.7f * v.x + 0.3f * nv.x;
            v.y = 0.7f * v.y + 0.3f * nv.y;
            v.z = 0.7f * v.z + 0.3f * nv.z;
            v.w = 0.7f * v.w + 0.3f * nv.w;
        }
        outb[idx] = v;
    }
}

// ---------------------------------------------------------------------------
extern "C" void kernel_launch(void* const* d_in, const int* in_sizes, int n_in,
                              void* d_out, int out_size, void* d_ws, size_t ws_size,
                              hipStream_t stream)
{
    const float* cf  = (const float*)d_in[0];
    const float* em  = (const float*)d_in[1];
    const float* ipw = (const float*)d_in[2];
    const float* ipb = (const float*)d_in[3];
    const float* opw = (const float*)d_in[4];
    const float* opb = (const float*)d_in[5];
    const float* lng = (const float*)d_in[6];
    const float* lnb = (const float*)d_in[7];
    const float* w1  = (const float*)d_in[8];
    const float* b1  = (const float*)d_in[9];
    const float* w2  = (const float*)d_in[10];
    const float* b2  = (const float*)d_in[11];
    const float* gw  = (const float*)d_in[12];
    const float* gb  = (const float*)d_in[13];

    float* x   = (float*)d_out;                  // (B,T,D)
    float* emo = x + (size_t)BT_ * D_;           // (B,N,D)

    // workspace layout (bytes); qb aliases first half of h (q dead before FFN)
    char* w = (char*)d_ws;
    __hip_bfloat16* h    = (__hip_bfloat16*)w;   // 16384x2048 bf16 (64MB)
    __hip_bfloat16* qbuf = (__hip_bfloat16*)w;   // 16384x1024 bf16 (aliases h)
    w += 67108864;
    __hip_bfloat16* actb = (__hip_bfloat16*)w; w += 33554432;  // 16384x1024
    __hip_bfloat16* ipwb = (__hip_bfloat16*)w; w += 6291456;   // 3x1024x1024
    __hip_bfloat16* opwb = (__hip_bfloat16*)w; w += 2097152;   // 1024x1024
    __hip_bfloat16* w1b  = (__hip_bfloat16*)w; w += 12582912;  // 3x2048x1024
    __hip_bfloat16* w2b  = (__hip_bfloat16*)w; w += 12582912;  // 3x1024x2048
    __hip_bfloat16* emb  = (__hip_bfloat16*)w; w += 524288;    // 4x64x1024
    __hip_bfloat16* kbb  = (__hip_bfloat16*)w; w += 524288;
    __hip_bfloat16* vbb  = (__hip_bfloat16*)w; w += 524288;
    __hip_bfloat16* vtb  = (__hip_bfloat16*)w; w += 524288;    // [B,H,128,64]
    float* S  = (float*)w; w += 1024;            // 256 floats
    float* fs = (float*)w; w += 16384;           // 4096
    float* ms = (float*)w; w += 16384;
    float* nm = (float*)w; w += 16384;

    hipMemsetAsync(S, 0, (256 + 4096) * sizeof(float), stream);  // S + fs

    const dim3 blk(256);
    const dim3 blk512(512);

    // bf16 copies
    cvt_kernel<<<8192, blk, 0, stream>>>(cf, actb, BT_ * D_);
    cvt_kernel<<<128,  blk, 0, stream>>>(em, emb, B_ * N_ * D_);
    cvt_kernel<<<1536, blk, 0, stream>>>(ipw, ipwb, 3 * D_ * D_);
    cvt_kernel<<<512,  blk, 0, stream>>>(opw, opwb, D_ * D_);
    cvt_kernel<<<3072, blk, 0, stream>>>(w1, w1b, 3 * D2_ * D_);
    cvt_kernel<<<3072, blk, 0, stream>>>(w2, w2b, 3 * D_ * D2_);

    // projections (all bf16 MFMA, bf16 out)
    gemm_bf16_kernel<false, false, true><<<dim3(4, 64), blk512, 0, stream>>>(
        actb, ipwb, ipb, nullptr, qbuf, BT_, D_, D_);
    gemm_bf16_kernel<false, false, true><<<dim3(4, 1), blk512, 0, stream>>>(
        emb, ipwb + D_ * D_, ipb + D_, nullptr, kbb, B_ * N_, D_, D_);
    gemm_bf16_kernel<false, false, true><<<dim3(4, 1), blk512, 0, stream>>>(
        emb, ipwb + 2 * D_ * D_, ipb + 2 * D_, nullptr, vbb, B_ * N_, D_, D_);
    vtrans_kernel<<<B_ * H_, blk, 0, stream>>>(vbb, vtb);

    // attention: ctx (bf16) -> actb, S accumulated
    attn_mfma_kernel<<<dim3(T_ / 128, B_ * H_), blk, 0, stream>>>(
        qbuf, kbb, vtb, actb, S);

    // x = ctx @ out_proj^T + out_proj_b + cf
    gemm_bf16_kernel<false, true, false><<<dim3(4, 64), blk512, 0, stream>>>(
        actb, opwb, opb, cf, x, BT_, D_, D_);

    // 3 FFN layers
    for (int i = 0; i < 3; ++i) {
        ln_fused_kernel<<<BT_, blk, 0, stream>>>(
            x, lng + i * D_, lnb + i * D_, actb);
        gemm_bf16_kernel<true, false, true><<<dim3(8, 64), blk512, 0, stream>>>(
            actb, w1b + (size_t)i * D2_ * D_, b1 + i * D2_, nullptr, h,
            BT_, D2_, D_);
        gemm_bf16_kernel<false, true, false><<<dim3(4, 64), blk512, 0, stream>>>(
            h, w2b + (size_t)i * D_ * D2_, b2 + i * D_, x, x,
            BT_, D_, D2_);
    }

    // summaries + gate + top-k memory update
    frame_summary_kernel<<<dim3(B_, 4, 8), blk, 0, stream>>>(cf, fs);
    mem_summary_kernel<<<dim3(B_, 4), blk, 0, stream>>>(em, ms);
    gate_kernel<<<dim3(B_, 4), blk, 0, stream>>>(fs, ms, gw, gb, nm);
    topk_update_kernel<<<B_, blk, 0, stream>>>(S, em, nm, emo);
}

// Round 7
// 1138.561 us; speedup vs baseline: 6.0158x; 1.0240x over previous
//
#include <hip/hip_runtime.h>
#include <hip/hip_bf16.h>
#include <cmath>

// Problem dims (fixed by reference)
#define B_  4
#define T_  4096
#define D_  1024
#define N_  64
#define H_  8
#define HD_ 128
#define BT_ (B_*T_)      // 16384
#define D2_ 2048

typedef __attribute__((ext_vector_type(8))) short bfrag8;   // 8 x bf16 (4 VGPRs)
typedef __attribute__((ext_vector_type(4))) float f32x4;

__device__ __forceinline__ void gload_lds16(const void* g, void* l) {
    __builtin_amdgcn_global_load_lds(
        (const __attribute__((address_space(1))) unsigned int*)g,
        (__attribute__((address_space(3))) unsigned int*)l,
        16, 0, 0);
}

#define S_BARRIER()    __builtin_amdgcn_s_barrier()
#define WAIT_LGKM0()   { asm volatile("s_waitcnt lgkmcnt(0)" ::: "memory"); \
                         __builtin_amdgcn_sched_barrier(0); }
#define WAIT_VM(n)     asm volatile("s_waitcnt vmcnt(" #n ")" ::: "memory")

// ---------------------------------------------------------------------------
// bf16 MFMA GEMM, 256x256 tile, BK=64, 512 thr (8 waves 2Mx4N), double-buffered
// LDS (128 KiB), counted-vmcnt phase schedule (T3+T4) + T2 slot-XOR swizzle +
// T5 setprio. Per K-tile: 4 half-tile stages (Alo,Blo,Bhi,Ahi; 2 gload_lds
// each) spread over 3 phases; all steady-state waits are vmcnt(4)+s_barrier.
// Stages only ever target the buffer NOT being read this iteration.
// C[M,N] = act(A[M,K] @ W[N,K]^T + bias) (+res). M%256==0, N%256==0, K%64==0.
// ---------------------------------------------------------------------------
template<bool GELU, bool RES, bool OUTBF16>
__global__ __launch_bounds__(512, 2) void gemm_bf16_kernel(
    const __hip_bfloat16* __restrict__ A, const __hip_bfloat16* __restrict__ Wt,
    const float* __restrict__ bias, const float* __restrict__ res,
    void* __restrict__ Cout, int M, int N, int K)
{
    __shared__ short As[2 * 256 * 64];   // 64 KiB
    __shared__ short Bs[2 * 256 * 64];   // 64 KiB

    const int tid = threadIdx.x;
    const int lane = tid & 63;
    const int wid = tid >> 6;
    const int wr = wid >> 2;            // 0..1
    const int wc = wid & 3;             // 0..3

    // T1: XCD-aware block swizzle (only when nwg % 8 == 0); groups same-A-row
    // panels on one XCD for L2 reuse.
    const int nwg = gridDim.x * gridDim.y;
    int lin = blockIdx.y * gridDim.x + blockIdx.x;
    if ((nwg & 7) == 0) lin = (lin & 7) * (nwg >> 3) + (lin >> 3);
    const int by = lin / gridDim.x;
    const int bx = lin - by * gridDim.x;
    const int m0 = by * 256;
    const int n0 = bx * 256;

    const short* Ag = (const short*)A + (size_t)m0 * K;
    const short* Bg = (const short*)Wt + (size_t)n0 * K;

    const int frow = lane & 15;
    const int fk8  = lane >> 4;          // 0..3

    // stage half-tile h (0=rows 0-127, 1=rows 128-255) of K-tile t
    auto STAGE_A = [&](int t, int h) {
        const int kb = t << 6;
        short* Lb = &As[(t & 1) * 16384 + h * 8192];
#pragma unroll
        for (int s = 0; s < 2; ++s) {
            const int L = s * 512 + tid;
            const int row = h * 128 + (L >> 3), p = L & 7;
            gload_lds16(Ag + (size_t)row * K + kb + ((p ^ (row & 7)) << 3), &Lb[L * 8]);
        }
    };
    auto STAGE_B = [&](int t, int h) {
        const int kb = t << 6;
        short* Lb = &Bs[(t & 1) * 16384 + h * 8192];
#pragma unroll
        for (int s = 0; s < 2; ++s) {
            const int L = s * 512 + tid;
            const int row = h * 128 + (L >> 3), p = L & 7;
            gload_lds16(Bg + (size_t)row * K + kb + ((p ^ (row & 7)) << 3), &Lb[L * 8]);
        }
    };

    // fragment loads; i/j row-col mapping keeps each phase's reads within one
    // staged half-tile: arow(i) = wr*64 + (i&3)*16 + (i>>2)*128  (i<4 -> lo)
    //                   bcol(j) = wc*32 + (j&1)*16 + (j>>1)*128  (j<2 -> lo)
    auto LDA = [&](int t, int i, int kk) -> bfrag8 {
        const int row = wr * 64 + (i & 3) * 16 + (i >> 2) * 128 + frow;
        return *(const bfrag8*)&As[(t & 1) * 16384 + row * 64 +
                                   (((kk * 4 + fk8) ^ (row & 7)) << 3)];
    };
    auto LDB = [&](int t, int j, int kk) -> bfrag8 {
        const int row = wc * 32 + (j & 1) * 16 + (j >> 1) * 128 + frow;
        return *(const bfrag8*)&Bs[(t & 1) * 16384 + row * 64 +
                                   (((kk * 4 + fk8) ^ (row & 7)) << 3)];
    };

    f32x4 acc[8][4] = {};
    bfrag8 aF[4][2], bF[4][2];

    const int nt = K >> 6;

    // prologue: stage tile 0 in order Alo, Blo, Bhi, Ahi
    STAGE_A(0, 0); STAGE_B(0, 0); STAGE_B(0, 1); STAGE_A(0, 1);
    WAIT_VM(4);                 // Alo,Blo landed (this wave)
    S_BARRIER();                // ... and all waves'

    for (int t = 0; t < nt; ++t) {
        const bool nx = (t + 1 < nt);
        // ---- phase 1: read Alo+Blo, stage next Alo, MFMA lo x j01 ----
#pragma unroll
        for (int ii = 0; ii < 4; ++ii) { aF[ii][0] = LDA(t, ii, 0); aF[ii][1] = LDA(t, ii, 1); }
#pragma unroll
        for (int j = 0; j < 2; ++j)    { bF[j][0] = LDB(t, j, 0);  bF[j][1] = LDB(t, j, 1); }
        if (nx) STAGE_A(t + 1, 0);
        S_BARRIER();
        WAIT_LGKM0();
        __builtin_amdgcn_s_setprio(1);
#pragma unroll
        for (int ii = 0; ii < 4; ++ii)
#pragma unroll
            for (int j = 0; j < 2; ++j) {
                acc[ii][j] = __builtin_amdgcn_mfma_f32_16x16x32_bf16(aF[ii][0], bF[j][0], acc[ii][j], 0, 0, 0);
                acc[ii][j] = __builtin_amdgcn_mfma_f32_16x16x32_bf16(aF[ii][1], bF[j][1], acc[ii][j], 0, 0, 0);
            }
        __builtin_amdgcn_s_setprio(0);
        if (nx) { WAIT_VM(4); } else { WAIT_VM(2); }   // Bhi landed
        S_BARRIER();

        // ---- phase 2: read Bhi, stage next Blo, MFMA lo x j23 ----
#pragma unroll
        for (int j = 2; j < 4; ++j)    { bF[j][0] = LDB(t, j, 0);  bF[j][1] = LDB(t, j, 1); }
        if (nx) STAGE_B(t + 1, 0);
        S_BARRIER();
        WAIT_LGKM0();
        __builtin_amdgcn_s_setprio(1);
#pragma unroll
        for (int ii = 0; ii < 4; ++ii)
#pragma unroll
            for (int j = 2; j < 4; ++j) {
                acc[ii][j] = __builtin_amdgcn_mfma_f32_16x16x32_bf16(aF[ii][0], bF[j][0], acc[ii][j], 0, 0, 0);
                acc[ii][j] = __builtin_amdgcn_mfma_f32_16x16x32_bf16(aF[ii][1], bF[j][1], acc[ii][j], 0, 0, 0);
            }
        __builtin_amdgcn_s_setprio(0);
        if (nx) { WAIT_VM(4); } else { WAIT_VM(0); }   // Ahi landed
        S_BARRIER();

        // ---- phase 3: read Ahi, stage next Bhi+Ahi, MFMA hi x j0123 ----
#pragma unroll
        for (int ii = 0; ii < 4; ++ii) { aF[ii][0] = LDA(t, 4 + ii, 0); aF[ii][1] = LDA(t, 4 + ii, 1); }
        if (nx) { STAGE_B(t + 1, 1); STAGE_A(t + 1, 1); }
        S_BARRIER();
        WAIT_LGKM0();
        __builtin_amdgcn_s_setprio(1);
#pragma unroll
        for (int ii = 0; ii < 4; ++ii)
#pragma unroll
            for (int j = 0; j < 4; ++j) {
                acc[4 + ii][j] = __builtin_amdgcn_mfma_f32_16x16x32_bf16(aF[ii][0], bF[j][0], acc[4 + ii][j], 0, 0, 0);
                acc[4 + ii][j] = __builtin_amdgcn_mfma_f32_16x16x32_bf16(aF[ii][1], bF[j][1], acc[4 + ii][j], 0, 0, 0);
            }
        __builtin_amdgcn_s_setprio(0);
        if (nx) { WAIT_VM(4); }       // next Alo,Blo landed
        S_BARRIER();
    }

    // epilogue: C/D map col=lane&15, row=(lane>>4)*4+reg
    float bias4[4];
#pragma unroll
    for (int j = 0; j < 4; ++j)
        bias4[j] = bias[n0 + wc * 32 + (j & 1) * 16 + (j >> 1) * 128 + (lane & 15)];
#pragma unroll
    for (int i = 0; i < 8; ++i) {
        const int rbase = m0 + wr * 64 + (i & 3) * 16 + (i >> 2) * 128 + (lane >> 4) * 4;
#pragma unroll
        for (int r = 0; r < 4; ++r) {
            const size_t rowoff = (size_t)(rbase + r) * N;
#pragma unroll
            for (int j = 0; j < 4; ++j) {
                const int col = n0 + wc * 32 + (j & 1) * 16 + (j >> 1) * 128 + (lane & 15);
                float v = acc[i][j][r] + bias4[j];
                if (GELU) v = 0.5f * v * (1.0f + erff(v * 0.70710678118654752f));
                if (RES)  v += res[rowoff + col];
                if (OUTBF16) ((__hip_bfloat16*)Cout)[rowoff + col] = __float2bfloat16(v);
                else         ((float*)Cout)[rowoff + col] = v;
            }
        }
    }
}

// ---------------------------------------------------------------------------
// fp32 -> bf16 conversion, 8 elems/thread
// ---------------------------------------------------------------------------
__global__ __launch_bounds__(256) void cvt_kernel(
    const float* __restrict__ in, __hip_bfloat16* __restrict__ out, int n)
{
    const int i = (blockIdx.x * 256 + threadIdx.x) * 8;
    if (i >= n) return;
    const float4 v0 = *(const float4*)&in[i];
    const float4 v1 = *(const float4*)&in[i + 4];
    __hip_bfloat16 o[8];
    o[0] = __float2bfloat16(v0.x); o[1] = __float2bfloat16(v0.y);
    o[2] = __float2bfloat16(v0.z); o[3] = __float2bfloat16(v0.w);
    o[4] = __float2bfloat16(v1.x); o[5] = __float2bfloat16(v1.y);
    o[6] = __float2bfloat16(v1.z); o[7] = __float2bfloat16(v1.w);
    *(uint4*)&out[i] = *(uint4*)o;
}

// ---------------------------------------------------------------------------
// Fused LayerNorm (stats + apply) -> bf16. One block per row of 1024.
// ---------------------------------------------------------------------------
__global__ __launch_bounds__(256) void ln_fused_kernel(
    const float* __restrict__ x, const float* __restrict__ g,
    const float* __restrict__ be, __hip_bfloat16* __restrict__ out)
{
    const int m = blockIdx.x;
    const int c = threadIdx.x * 4;
    const float4 v = *(const float4*)&x[(size_t)m * D_ + c];
    float s = v.x + v.y + v.z + v.w;
    float ss = v.x * v.x + v.y * v.y + v.z * v.z + v.w * v.w;
#pragma unroll
    for (int off = 32; off; off >>= 1) {
        s += __shfl_xor(s, off);
        ss += __shfl_xor(ss, off);
    }
    __shared__ float bs[4], bss[4];
    const int wave = threadIdx.x >> 6;
    if ((threadIdx.x & 63) == 0) { bs[wave] = s; bss[wave] = ss; }
    __syncthreads();
    const float S = bs[0] + bs[1] + bs[2] + bs[3];
    const float SS = bss[0] + bss[1] + bss[2] + bss[3];
    const float mean = S * (1.0f / D_);
    const float rstd = rsqrtf(SS * (1.0f / D_) - mean * mean + 1e-5f);
    const float4 gg = *(const float4*)&g[c];
    const float4 bb = *(const float4*)&be[c];
    __hip_bfloat16 o[4];
    o[0] = __float2bfloat16((v.x - mean) * rstd * gg.x + bb.x);
    o[1] = __float2bfloat16((v.y - mean) * rstd * gg.y + bb.y);
    o[2] = __float2bfloat16((v.z - mean) * rstd * gg.z + bb.z);
    o[3] = __float2bfloat16((v.w - mean) * rstd * gg.w + bb.w);
    *(uint2*)&out[(size_t)m * D_ + c] = *(uint2*)o;
}

// ---------------------------------------------------------------------------
// V transpose: vtb[b,h,d,n] = vbb[b,n,h*128+d]  (bf16 -> bf16)
// ---------------------------------------------------------------------------
__global__ __launch_bounds__(256) void vtrans_kernel(
    const __hip_bfloat16* __restrict__ vbb, __hip_bfloat16* __restrict__ vtb)
{
    const int bh = blockIdx.x;
    const int b = bh >> 3, h = bh & 7;
    for (int ii = threadIdx.x; ii < HD_ * N_; ii += 256) {
        const int d = ii >> 6, n = ii & 63;
        vtb[(size_t)bh * (HD_ * N_) + ii] =
            vbb[(size_t)(b * N_ + n) * D_ + h * HD_ + d];
    }
}

// ---------------------------------------------------------------------------
// MFMA attention: one block = one (b,h) x 128 t-rows. N=64 keys fit fully.
// LDS tiles XOR-swizzled (slot8 ^= row&7) with pre-swizzled global sources.
// Writes ctx bf16 (coalesced via LDS), accumulates S[b][n].
// ---------------------------------------------------------------------------
__global__ __launch_bounds__(256) void attn_mfma_kernel(
    const __hip_bfloat16* __restrict__ qb, const __hip_bfloat16* __restrict__ kbb,
    const __hip_bfloat16* __restrict__ vtb, __hip_bfloat16* __restrict__ ctxb,
    float* __restrict__ S)
{
    const int bh = blockIdx.y;
    const int b = bh >> 3, hh = bh & 7;
    const int t0 = blockIdx.x * 128;

    __shared__ short Ql[128 * 128];          // reused as ctx staging later
    __shared__ short Kl[64 * 128];
    __shared__ short Vtl[128 * 64];
    __shared__ __hip_bfloat16 Pl[128 * 64];

    const int tid = threadIdx.x;
    const int lane = tid & 63;
    const int wid = tid >> 6;

    // ---- stage Q (32 KiB), K (16 KiB), Vt (16 KiB) ----
    const short* qg = (const short*)qb;
    for (int s = wid; s < 32; s += 4) {
        const int row = 4 * s + (lane >> 4);
        const int col8 = (lane & 15) ^ (row & 7);
        gload_lds16(qg + ((size_t)(b * T_ + t0 + row)) * D_ + hh * HD_ + col8 * 8,
                    &Ql[s * 512 + lane * 8]);
    }
    const short* kg = (const short*)kbb;
    for (int s = wid; s < 16; s += 4) {
        const int row = 4 * s + (lane >> 4);
        const int col8 = (lane & 15) ^ (row & 7);
        gload_lds16(kg + ((size_t)(b * N_ + row)) * D_ + hh * HD_ + col8 * 8,
                    &Kl[s * 512 + lane * 8]);
    }
    const short* vg = (const short*)vtb + (size_t)bh * (HD_ * N_);
    for (int s = wid; s < 16; s += 4) {
        const int row = 8 * s + (lane >> 3);
        const int col8 = (lane & 7) ^ (row & 7);
        gload_lds16(vg + row * 64 + col8 * 8, &Vtl[s * 512 + lane * 8]);
    }
    __syncthreads();

    const int frow = lane & 15;
    const int fk8  = lane >> 4;      // 0..3

    // ---- QK^T: per wave rows wid*32..+31, acc[2][4] over 64 key-cols ----
    f32x4 acc[2][4] = {};
#pragma unroll
    for (int ks = 0; ks < 4; ++ks) {
        bfrag8 a[2], bf[4];
#pragma unroll
        for (int i = 0; i < 2; ++i) {
            const int row = wid * 32 + i * 16 + frow;
            const int col8 = (ks * 4 + fk8) ^ (row & 7);
            a[i] = *(const bfrag8*)&Ql[row * 128 + col8 * 8];
        }
#pragma unroll
        for (int j = 0; j < 4; ++j) {
            const int row = j * 16 + frow;
            const int col8 = (ks * 4 + fk8) ^ (row & 7);
            bf[j] = *(const bfrag8*)&Kl[row * 128 + col8 * 8];
        }
#pragma unroll
        for (int i = 0; i < 2; ++i)
#pragma unroll
            for (int j = 0; j < 4; ++j)
                acc[i][j] = __builtin_amdgcn_mfma_f32_16x16x32_bf16(a[i], bf[j], acc[i][j], 0, 0, 0);
    }

    // ---- softmax over 64 cols, write P to LDS bf16 (swizzled) ----
    const float scale = 0.088388347648318441f;   // 1/sqrt(128)
    float accS[4] = {0.f, 0.f, 0.f, 0.f};
#pragma unroll
    for (int i = 0; i < 2; ++i) {
#pragma unroll
        for (int r = 0; r < 4; ++r) {
            float sv[4];
            float m = -INFINITY;
#pragma unroll
            for (int j = 0; j < 4; ++j) { sv[j] = acc[i][j][r] * scale; m = fmaxf(m, sv[j]); }
#pragma unroll
            for (int off = 1; off < 16; off <<= 1) m = fmaxf(m, __shfl_xor(m, off));
            float sum = 0.f;
#pragma unroll
            for (int j = 0; j < 4; ++j) { sv[j] = __expf(sv[j] - m); sum += sv[j]; }
#pragma unroll
            for (int off = 1; off < 16; off <<= 1) sum += __shfl_xor(sum, off);
            const float inv = 1.0f / sum;
            const int row = wid * 32 + i * 16 + (lane >> 4) * 4 + r;
#pragma unroll
            for (int j = 0; j < 4; ++j) {
                const float pn = sv[j] * inv;
                accS[j] += pn;
                const int col = j * 16 + (lane & 15);
                Pl[row * 64 + (((col >> 3) ^ (row & 7)) << 3) + (col & 7)] = __float2bfloat16(pn);
            }
        }
    }
    // attn-mean accumulation for top-k
#pragma unroll
    for (int j = 0; j < 4; ++j) {
        float v = accS[j];
        v += __shfl_xor(v, 16);
        v += __shfl_xor(v, 32);
        if (lane < 16)
            atomicAdd(&S[b * N_ + j * 16 + lane], v * (1.0f / (H_ * (float)T_)));
    }
    __syncthreads();

    // ---- PV: ctx[128 x 128] = P[128 x 64] @ V[64 x 128] (Vt as W) ----
    f32x4 acc2[2][8] = {};
#pragma unroll
    for (int ks = 0; ks < 2; ++ks) {
        bfrag8 pa[2];
#pragma unroll
        for (int i = 0; i < 2; ++i) {
            const int row = wid * 32 + i * 16 + frow;
            const int col8 = (ks * 4 + fk8) ^ (row & 7);
            pa[i] = *(const bfrag8*)&Pl[row * 64 + col8 * 8];
        }
#pragma unroll
        for (int j = 0; j < 8; ++j) {
            const int row = j * 16 + frow;   // d index
            const int col8 = (ks * 4 + fk8) ^ (row & 7);
            const bfrag8 vv = *(const bfrag8*)&Vtl[row * 64 + col8 * 8];
#pragma unroll
            for (int i = 0; i < 2; ++i)
                acc2[i][j] = __builtin_amdgcn_mfma_f32_16x16x32_bf16(pa[i], vv, acc2[i][j], 0, 0, 0);
        }
    }

    // ---- ctx -> LDS (reuse Ql) -> coalesced bf16 global write ----
    short* Cl = Ql;
#pragma unroll
    for (int i = 0; i < 2; ++i)
#pragma unroll
        for (int r = 0; r < 4; ++r) {
            const int row = wid * 32 + i * 16 + (lane >> 4) * 4 + r;
#pragma unroll
            for (int j = 0; j < 8; ++j) {
                __hip_bfloat16 hv = __float2bfloat16(acc2[i][j][r]);
                Cl[row * 128 + j * 16 + (lane & 15)] = *(short*)&hv;
            }
        }
    __syncthreads();
    short* cg = (short*)ctxb;
#pragma unroll
    for (int s = 0; s < 8; ++s) {
        const int c = s * 256 + tid;        // 2048 chunks of 16B
        const int row = c >> 4;
        const int slot = c & 15;
        *(uint4*)&cg[((size_t)(b * T_ + t0 + row)) * D_ + hh * HD_ + slot * 8] =
            *(const uint4*)&Cl[row * 128 + slot * 8];
    }
}

// ---------------------------------------------------------------------------
__global__ __launch_bounds__(256) void frame_summary_kernel(
    const float* __restrict__ cf, float* __restrict__ fs)
{
    const int b = blockIdx.x;
    const int d = blockIdx.y * 256 + threadIdx.x;
    const int t0 = blockIdx.z * 512;
    float s = 0.0f;
    for (int t = t0; t < t0 + 512; ++t)
        s += cf[((size_t)(b * T_ + t)) * D_ + d];
    atomicAdd(&fs[b * D_ + d], s * (1.0f / (float)T_));
}

__global__ __launch_bounds__(256) void mem_summary_kernel(
    const float* __restrict__ em, float* __restrict__ ms)
{
    const int b = blockIdx.x;
    const int d = blockIdx.y * 256 + threadIdx.x;
    float s = 0.0f;
#pragma unroll 4
    for (int n = 0; n < N_; ++n)
        s += em[((size_t)(b * N_ + n)) * D_ + d];
    ms[b * D_ + d] = s * (1.0f / (float)N_);
}

__global__ __launch_bounds__(256) void gate_kernel(
    const float* __restrict__ fs, const float* __restrict__ ms,
    const float* __restrict__ gw, const float* __restrict__ gb,
    float* __restrict__ nm)
{
    const int b = blockIdx.x;
    const int d = blockIdx.y * 256 + threadIdx.x;
    const float* wrow = gw + (size_t)d * D2_;
    const float* f = fs + b * D_;
    const float* mm = ms + b * D_;
    float g = gb[d];
    for (int j = 0; j < D_; ++j) g += f[j] * wrow[j];
    for (int j = 0; j < D_; ++j) g += mm[j] * wrow[D_ + j];
    const float sig = 1.0f / (1.0f + __expf(-g));
    nm[b * D_ + d] = sig * f[d] + (1.0f - sig) * mm[d];
}

__global__ __launch_bounds__(256) void topk_update_kernel(
    const float* __restrict__ S, const float* __restrict__ em,
    const float* __restrict__ nm, float* __restrict__ emo)
{
    const int b = blockIdx.x;
    __shared__ int topi[3];
    const int tid = threadIdx.x;
    if (tid < 64) {
        float sv = S[b * N_ + tid];
#pragma unroll
        for (int k = 0; k < 3; ++k) {
            float v = sv;
            int idx = tid;
#pragma unroll
            for (int off = 32; off; off >>= 1) {
                const float ov = __shfl_xor(v, off);
                const int oi = __shfl_xor(idx, off);
                if (ov > v || (ov == v && oi < idx)) { v = ov; idx = oi; }
            }
            if (tid == 0) topi[k] = idx;
            if (tid == idx) sv = -INFINITY;
        }
    }
    __syncthreads();
    const int i0 = topi[0], i1 = topi[1], i2 = topi[2];
    const float4* emb = (const float4*)(em + (size_t)b * N_ * D_);
    const float4* nmb = (const float4*)(nm + (size_t)b * D_);
    float4* outb = (float4*)(emo + (size_t)b * N_ * D_);
    for (int idx = tid; idx < N_ * D_ / 4; idx += 256) {
        const int n = idx >> 8;
        const int d4 = idx & 255;
        float4 v = emb[idx];
        if (n == i0 || n == i1 || n == i2) {
            const float4 nv = nmb[d4];
            v.x = 0.7f * v.x + 0.3f * nv.x;
            v.y = 0.7f * v.y + 0.3f * nv.y;
            v.z = 0.7f * v.z + 0.3f * nv.z;
            v.w = 0.7f * v.w + 0.3f * nv.w;
        }
        outb[idx] = v;
    }
}

// ---------------------------------------------------------------------------
extern "C" void kernel_launch(void* const* d_in, const int* in_sizes, int n_in,
                              void* d_out, int out_size, void* d_ws, size_t ws_size,
                              hipStream_t stream)
{
    const float* cf  = (const float*)d_in[0];
    const float* em  = (const float*)d_in[1];
    const float* ipw = (const float*)d_in[2];
    const float* ipb = (const float*)d_in[3];
    const float* opw = (const float*)d_in[4];
    const float* opb = (const float*)d_in[5];
    const float* lng = (const float*)d_in[6];
    const float* lnb = (const float*)d_in[7];
    const float* w1  = (const float*)d_in[8];
    const float* b1  = (const float*)d_in[9];
    const float* w2  = (const float*)d_in[10];
    const float* b2  = (const float*)d_in[11];
    const float* gw  = (const float*)d_in[12];
    const float* gb  = (const float*)d_in[13];

    float* x   = (float*)d_out;                  // (B,T,D)
    float* emo = x + (size_t)BT_ * D_;           // (B,N,D)

    // workspace layout (bytes); qb aliases first half of h (q dead before FFN)
    char* w = (char*)d_ws;
    __hip_bfloat16* h    = (__hip_bfloat16*)w;   // 16384x2048 bf16 (64MB)
    __hip_bfloat16* qbuf = (__hip_bfloat16*)w;   // 16384x1024 bf16 (aliases h)
    w += 67108864;
    __hip_bfloat16* actb = (__hip_bfloat16*)w; w += 33554432;  // 16384x1024
    __hip_bfloat16* ipwb = (__hip_bfloat16*)w; w += 6291456;   // 3x1024x1024
    __hip_bfloat16* opwb = (__hip_bfloat16*)w; w += 2097152;   // 1024x1024
    __hip_bfloat16* w1b  = (__hip_bfloat16*)w; w += 12582912;  // 3x2048x1024
    __hip_bfloat16* w2b  = (__hip_bfloat16*)w; w += 12582912;  // 3x1024x2048
    __hip_bfloat16* emb  = (__hip_bfloat16*)w; w += 524288;    // 4x64x1024
    __hip_bfloat16* kbb  = (__hip_bfloat16*)w; w += 524288;
    __hip_bfloat16* vbb  = (__hip_bfloat16*)w; w += 524288;
    __hip_bfloat16* vtb  = (__hip_bfloat16*)w; w += 524288;    // [B,H,128,64]
    float* S  = (float*)w; w += 1024;            // 256 floats
    float* fs = (float*)w; w += 16384;           // 4096
    float* ms = (float*)w; w += 16384;
    float* nm = (float*)w; w += 16384;

    hipMemsetAsync(S, 0, (256 + 4096) * sizeof(float), stream);  // S + fs

    const dim3 blk(256);
    const dim3 blk512(512);

    // bf16 copies
    cvt_kernel<<<8192, blk, 0, stream>>>(cf, actb, BT_ * D_);
    cvt_kernel<<<128,  blk, 0, stream>>>(em, emb, B_ * N_ * D_);
    cvt_kernel<<<1536, blk, 0, stream>>>(ipw, ipwb, 3 * D_ * D_);
    cvt_kernel<<<512,  blk, 0, stream>>>(opw, opwb, D_ * D_);
    cvt_kernel<<<3072, blk, 0, stream>>>(w1, w1b, 3 * D2_ * D_);
    cvt_kernel<<<3072, blk, 0, stream>>>(w2, w2b, 3 * D_ * D2_);

    // projections (all bf16 MFMA, bf16 out)
    gemm_bf16_kernel<false, false, true><<<dim3(4, 64), blk512, 0, stream>>>(
        actb, ipwb, ipb, nullptr, qbuf, BT_, D_, D_);
    gemm_bf16_kernel<false, false, true><<<dim3(4, 1), blk512, 0, stream>>>(
        emb, ipwb + D_ * D_, ipb + D_, nullptr, kbb, B_ * N_, D_, D_);
    gemm_bf16_kernel<false, false, true><<<dim3(4, 1), blk512, 0, stream>>>(
        emb, ipwb + 2 * D_ * D_, ipb + 2 * D_, nullptr, vbb, B_ * N_, D_, D_);
    vtrans_kernel<<<B_ * H_, blk, 0, stream>>>(vbb, vtb);

    // attention: ctx (bf16) -> actb, S accumulated
    attn_mfma_kernel<<<dim3(T_ / 128, B_ * H_), blk, 0, stream>>>(
        qbuf, kbb, vtb, actb, S);

    // x = ctx @ out_proj^T + out_proj_b + cf
    gemm_bf16_kernel<false, true, false><<<dim3(4, 64), blk512, 0, stream>>>(
        actb, opwb, opb, cf, x, BT_, D_, D_);

    // 3 FFN layers
    for (int i = 0; i < 3; ++i) {
        ln_fused_kernel<<<BT_, blk, 0, stream>>>(
            x, lng + i * D_, lnb + i * D_, actb);
        gemm_bf16_kernel<true, false, true><<<dim3(8, 64), blk512, 0, stream>>>(
            actb, w1b + (size_t)i * D2_ * D_, b1 + i * D2_, nullptr, h,
            BT_, D2_, D_);
        gemm_bf16_kernel<false, true, false><<<dim3(4, 64), blk512, 0, stream>>>(
            h, w2b + (size_t)i * D_ * D2_, b2 + i * D_, x, x,
            BT_, D_, D2_);
    }

    // summaries + gate + top-k memory update
    frame_summary_kernel<<<dim3(B_, 4, 8), blk, 0, stream>>>(cf, fs);
    mem_summary_kernel<<<dim3(B_, 4), blk, 0, stream>>>(em, ms);
    gate_kernel<<<dim3(B_, 4), blk, 0, stream>>>(fs, ms, gw, gb, nm);
    topk_update_kernel<<<B_, blk, 0, stream>>>(S, em, nm, emo);
}

// Round 8
// 1124.329 us; speedup vs baseline: 6.0920x; 1.0127x over previous
//
#include <hip/hip_runtime.h>
#include <hip/hip_bf16.h>
#include <cmath>

// Problem dims (fixed by reference)
#define B_  4
#define T_  4096
#define D_  1024
#define N_  64
#define H_  8
#define HD_ 128
#define BT_ (B_*T_)      // 16384
#define D2_ 2048

typedef __attribute__((ext_vector_type(8))) short bfrag8;   // 8 x bf16 (4 VGPRs)
typedef __attribute__((ext_vector_type(4))) float f32x4;

__device__ __forceinline__ void gload_lds16(const void* g, void* l) {
    __builtin_amdgcn_global_load_lds(
        (const __attribute__((address_space(1))) unsigned int*)g,
        (__attribute__((address_space(3))) unsigned int*)l,
        16, 0, 0);
}

// ---------------------------------------------------------------------------
// bf16 MFMA GEMM, 128x128 tile, BK=64, 256 thr (4 waves 2x2), single-buffer
// 32 KiB LDS -> 5 blocks/CU (m97-style cross-block overlap) + T2 chunk-XOR
// swizzle (stage source pre-swizzled, fragment reads swizzled; row stride
// 128B would otherwise be a 16-way bank conflict).
// C[M,N] = act(A[M,K] @ W[N,K]^T + bias) (+res). M%128==0, N%128==0, K%64==0.
// ---------------------------------------------------------------------------
template<bool GELU, bool RES, bool OUTBF16>
__global__ __launch_bounds__(256) void gemm_bf16_kernel(
    const __hip_bfloat16* __restrict__ A, const __hip_bfloat16* __restrict__ Wt,
    const float* __restrict__ bias, const float* __restrict__ res,
    void* __restrict__ Cout, int M, int N, int K)
{
    __shared__ short As[128 * 64];   // 16 KiB
    __shared__ short Bs[128 * 64];   // 16 KiB

    const int tid = threadIdx.x;
    const int lane = tid & 63;
    const int wid = tid >> 6;
    const int wr = wid >> 1, wc = wid & 1;   // wave -> 64x64 quadrant

    // T1: XCD-aware block swizzle (only when nwg % 8 == 0)
    const int nwg = gridDim.x * gridDim.y;
    int lin = blockIdx.y * gridDim.x + blockIdx.x;
    if ((nwg & 7) == 0) lin = (lin & 7) * (nwg >> 3) + (lin >> 3);
    const int by = lin / gridDim.x;
    const int bx = lin - by * gridDim.x;
    const int m0 = by * 128;
    const int n0 = bx * 128;

    const short* Ag = (const short*)A + (size_t)m0 * K;
    const short* Bg = (const short*)Wt + (size_t)n0 * K;

    const int frow = lane & 15;
    const int fk8  = lane >> 4;      // 0..3

    f32x4 acc[4][4] = {};

    for (int kb = 0; kb < K; kb += 64) {
        __syncthreads();             // previous iteration's reads done
        // stage A,B tiles: 128 rows x 64 cols bf16 = 8 chunks(16B)/row.
        // LDS dest linear; global source chunk = p ^ (row&7)  (rule 21)
#pragma unroll
        for (int s = 0; s < 4; ++s) {
            const int L = s * 256 + tid;
            const int row = L >> 3, p = L & 7;
            gload_lds16(Ag + (size_t)row * K + kb + ((p ^ (row & 7)) << 3), &As[L * 8]);
        }
#pragma unroll
        for (int s = 0; s < 4; ++s) {
            const int L = s * 256 + tid;
            const int row = L >> 3, p = L & 7;
            gload_lds16(Bg + (size_t)row * K + kb + ((p ^ (row & 7)) << 3), &Bs[L * 8]);
        }
        __syncthreads();             // compiler drains vmcnt before barrier

#pragma unroll
        for (int kk = 0; kk < 2; ++kk) {
            bfrag8 a[4], b[4];
#pragma unroll
            for (int i = 0; i < 4; ++i) {
                const int row = wr * 64 + i * 16 + frow;
                a[i] = *(const bfrag8*)&As[row * 64 + (((kk * 4 + fk8) ^ (row & 7)) << 3)];
            }
#pragma unroll
            for (int j = 0; j < 4; ++j) {
                const int row = wc * 64 + j * 16 + frow;
                b[j] = *(const bfrag8*)&Bs[row * 64 + (((kk * 4 + fk8) ^ (row & 7)) << 3)];
            }
#pragma unroll
            for (int i = 0; i < 4; ++i)
#pragma unroll
                for (int j = 0; j < 4; ++j)
                    acc[i][j] = __builtin_amdgcn_mfma_f32_16x16x32_bf16(a[i], b[j], acc[i][j], 0, 0, 0);
        }
    }

    // epilogue: C/D map col=lane&15, row=(lane>>4)*4+reg
#pragma unroll
    for (int i = 0; i < 4; ++i) {
        const int rbase = m0 + wr * 64 + i * 16 + (lane >> 4) * 4;
#pragma unroll
        for (int r = 0; r < 4; ++r) {
            const size_t rowoff = (size_t)(rbase + r) * N;
#pragma unroll
            for (int j = 0; j < 4; ++j) {
                const int col = n0 + wc * 64 + j * 16 + (lane & 15);
                float v = acc[i][j][r] + bias[col];
                if (GELU) v = 0.5f * v * (1.0f + erff(v * 0.70710678118654752f));
                if (RES)  v += res[rowoff + col];
                if (OUTBF16) ((__hip_bfloat16*)Cout)[rowoff + col] = __float2bfloat16(v);
                else         ((float*)Cout)[rowoff + col] = v;
            }
        }
    }
}

// ---------------------------------------------------------------------------
// fp32 -> bf16 conversion, 8 elems/thread
// ---------------------------------------------------------------------------
__global__ __launch_bounds__(256) void cvt_kernel(
    const float* __restrict__ in, __hip_bfloat16* __restrict__ out, int n)
{
    const int i = (blockIdx.x * 256 + threadIdx.x) * 8;
    if (i >= n) return;
    const float4 v0 = *(const float4*)&in[i];
    const float4 v1 = *(const float4*)&in[i + 4];
    __hip_bfloat16 o[8];
    o[0] = __float2bfloat16(v0.x); o[1] = __float2bfloat16(v0.y);
    o[2] = __float2bfloat16(v0.z); o[3] = __float2bfloat16(v0.w);
    o[4] = __float2bfloat16(v1.x); o[5] = __float2bfloat16(v1.y);
    o[6] = __float2bfloat16(v1.z); o[7] = __float2bfloat16(v1.w);
    *(uint4*)&out[i] = *(uint4*)o;
}

// ---------------------------------------------------------------------------
// Fused LayerNorm (stats + apply) -> bf16. One block per row of 1024.
// ---------------------------------------------------------------------------
__global__ __launch_bounds__(256) void ln_fused_kernel(
    const float* __restrict__ x, const float* __restrict__ g,
    const float* __restrict__ be, __hip_bfloat16* __restrict__ out)
{
    const int m = blockIdx.x;
    const int c = threadIdx.x * 4;
    const float4 v = *(const float4*)&x[(size_t)m * D_ + c];
    float s = v.x + v.y + v.z + v.w;
    float ss = v.x * v.x + v.y * v.y + v.z * v.z + v.w * v.w;
#pragma unroll
    for (int off = 32; off; off >>= 1) {
        s += __shfl_xor(s, off);
        ss += __shfl_xor(ss, off);
    }
    __shared__ float bs[4], bss[4];
    const int wave = threadIdx.x >> 6;
    if ((threadIdx.x & 63) == 0) { bs[wave] = s; bss[wave] = ss; }
    __syncthreads();
    const float S = bs[0] + bs[1] + bs[2] + bs[3];
    const float SS = bss[0] + bss[1] + bss[2] + bss[3];
    const float mean = S * (1.0f / D_);
    const float rstd = rsqrtf(SS * (1.0f / D_) - mean * mean + 1e-5f);
    const float4 gg = *(const float4*)&g[c];
    const float4 bb = *(const float4*)&be[c];
    __hip_bfloat16 o[4];
    o[0] = __float2bfloat16((v.x - mean) * rstd * gg.x + bb.x);
    o[1] = __float2bfloat16((v.y - mean) * rstd * gg.y + bb.y);
    o[2] = __float2bfloat16((v.z - mean) * rstd * gg.z + bb.z);
    o[3] = __float2bfloat16((v.w - mean) * rstd * gg.w + bb.w);
    *(uint2*)&out[(size_t)m * D_ + c] = *(uint2*)o;
}

// ---------------------------------------------------------------------------
// V transpose from fused KV buffer: vtb[b,h,d,n] = kv[(b*64+n)*2048 + 1024 + h*128 + d]
// ---------------------------------------------------------------------------
__global__ __launch_bounds__(256) void vtrans_kernel(
    const __hip_bfloat16* __restrict__ kv, __hip_bfloat16* __restrict__ vtb)
{
    const int bh = blockIdx.x;
    const int b = bh >> 3, h = bh & 7;
    for (int ii = threadIdx.x; ii < HD_ * N_; ii += 256) {
        const int d = ii >> 6, n = ii & 63;
        vtb[(size_t)bh * (HD_ * N_) + ii] =
            kv[(size_t)(b * N_ + n) * D2_ + 1024 + h * HD_ + d];
    }
}

// ---------------------------------------------------------------------------
// MFMA attention: one block = one (b,h) x 128 t-rows. N=64 keys fit fully.
// K read from fused KV buffer (row stride 2048, cols 0-1023).
// LDS tiles XOR-swizzled (slot8 ^= row&7) with pre-swizzled global sources.
// Writes ctx bf16 (coalesced via LDS), accumulates S[b][n].
// ---------------------------------------------------------------------------
__global__ __launch_bounds__(256) void attn_mfma_kernel(
    const __hip_bfloat16* __restrict__ qb, const __hip_bfloat16* __restrict__ kv,
    const __hip_bfloat16* __restrict__ vtb, __hip_bfloat16* __restrict__ ctxb,
    float* __restrict__ S)
{
    const int bh = blockIdx.y;
    const int b = bh >> 3, hh = bh & 7;
    const int t0 = blockIdx.x * 128;

    __shared__ short Ql[128 * 128];          // reused as ctx staging later
    __shared__ short Kl[64 * 128];
    __shared__ short Vtl[128 * 64];
    __shared__ __hip_bfloat16 Pl[128 * 64];

    const int tid = threadIdx.x;
    const int lane = tid & 63;
    const int wid = tid >> 6;

    // ---- stage Q (32 KiB), K (16 KiB), Vt (16 KiB) ----
    const short* qg = (const short*)qb;
    for (int s = wid; s < 32; s += 4) {
        const int row = 4 * s + (lane >> 4);
        const int col8 = (lane & 15) ^ (row & 7);
        gload_lds16(qg + ((size_t)(b * T_ + t0 + row)) * D_ + hh * HD_ + col8 * 8,
                    &Ql[s * 512 + lane * 8]);
    }
    const short* kg = (const short*)kv;
    for (int s = wid; s < 16; s += 4) {
        const int row = 4 * s + (lane >> 4);
        const int col8 = (lane & 15) ^ (row & 7);
        gload_lds16(kg + ((size_t)(b * N_ + row)) * D2_ + hh * HD_ + col8 * 8,
                    &Kl[s * 512 + lane * 8]);
    }
    const short* vg = (const short*)vtb + (size_t)bh * (HD_ * N_);
    for (int s = wid; s < 16; s += 4) {
        const int row = 8 * s + (lane >> 3);
        const int col8 = (lane & 7) ^ (row & 7);
        gload_lds16(vg + row * 64 + col8 * 8, &Vtl[s * 512 + lane * 8]);
    }
    __syncthreads();

    const int frow = lane & 15;
    const int fk8  = lane >> 4;      // 0..3

    // ---- QK^T: per wave rows wid*32..+31, acc[2][4] over 64 key-cols ----
    f32x4 acc[2][4] = {};
#pragma unroll
    for (int ks = 0; ks < 4; ++ks) {
        bfrag8 a[2], bf[4];
#pragma unroll
        for (int i = 0; i < 2; ++i) {
            const int row = wid * 32 + i * 16 + frow;
            const int col8 = (ks * 4 + fk8) ^ (row & 7);
            a[i] = *(const bfrag8*)&Ql[row * 128 + col8 * 8];
        }
#pragma unroll
        for (int j = 0; j < 4; ++j) {
            const int row = j * 16 + frow;
            const int col8 = (ks * 4 + fk8) ^ (row & 7);
            bf[j] = *(const bfrag8*)&Kl[row * 128 + col8 * 8];
        }
#pragma unroll
        for (int i = 0; i < 2; ++i)
#pragma unroll
            for (int j = 0; j < 4; ++j)
                acc[i][j] = __builtin_amdgcn_mfma_f32_16x16x32_bf16(a[i], bf[j], acc[i][j], 0, 0, 0);
    }

    // ---- softmax over 64 cols, write P to LDS bf16 (swizzled) ----
    const float scale = 0.088388347648318441f;   // 1/sqrt(128)
    float accS[4] = {0.f, 0.f, 0.f, 0.f};
#pragma unroll
    for (int i = 0; i < 2; ++i) {
#pragma unroll
        for (int r = 0; r < 4; ++r) {
            float sv[4];
            float m = -INFINITY;
#pragma unroll
            for (int j = 0; j < 4; ++j) { sv[j] = acc[i][j][r] * scale; m = fmaxf(m, sv[j]); }
#pragma unroll
            for (int off = 1; off < 16; off <<= 1) m = fmaxf(m, __shfl_xor(m, off));
            float sum = 0.f;
#pragma unroll
            for (int j = 0; j < 4; ++j) { sv[j] = __expf(sv[j] - m); sum += sv[j]; }
#pragma unroll
            for (int off = 1; off < 16; off <<= 1) sum += __shfl_xor(sum, off);
            const float inv = 1.0f / sum;
            const int row = wid * 32 + i * 16 + (lane >> 4) * 4 + r;
#pragma unroll
            for (int j = 0; j < 4; ++j) {
                const float pn = sv[j] * inv;
                accS[j] += pn;
                const int col = j * 16 + (lane & 15);
                Pl[row * 64 + (((col >> 3) ^ (row & 7)) << 3) + (col & 7)] = __float2bfloat16(pn);
            }
        }
    }
    // attn-mean accumulation for top-k
#pragma unroll
    for (int j = 0; j < 4; ++j) {
        float v = accS[j];
        v += __shfl_xor(v, 16);
        v += __shfl_xor(v, 32);
        if (lane < 16)
            atomicAdd(&S[b * N_ + j * 16 + lane], v * (1.0f / (H_ * (float)T_)));
    }
    __syncthreads();

    // ---- PV: ctx[128 x 128] = P[128 x 64] @ V[64 x 128] (Vt as W) ----
    f32x4 acc2[2][8] = {};
#pragma unroll
    for (int ks = 0; ks < 2; ++ks) {
        bfrag8 pa[2];
#pragma unroll
        for (int i = 0; i < 2; ++i) {
            const int row = wid * 32 + i * 16 + frow;
            const int col8 = (ks * 4 + fk8) ^ (row & 7);
            pa[i] = *(const bfrag8*)&Pl[row * 64 + col8 * 8];
        }
#pragma unroll
        for (int j = 0; j < 8; ++j) {
            const int row = j * 16 + frow;   // d index
            const int col8 = (ks * 4 + fk8) ^ (row & 7);
            const bfrag8 vv = *(const bfrag8*)&Vtl[row * 64 + col8 * 8];
#pragma unroll
            for (int i = 0; i < 2; ++i)
                acc2[i][j] = __builtin_amdgcn_mfma_f32_16x16x32_bf16(pa[i], vv, acc2[i][j], 0, 0, 0);
        }
    }

    // ---- ctx -> LDS (reuse Ql) -> coalesced bf16 global write ----
    short* Cl = Ql;
#pragma unroll
    for (int i = 0; i < 2; ++i)
#pragma unroll
        for (int r = 0; r < 4; ++r) {
            const int row = wid * 32 + i * 16 + (lane >> 4) * 4 + r;
#pragma unroll
            for (int j = 0; j < 8; ++j) {
                __hip_bfloat16 hv = __float2bfloat16(acc2[i][j][r]);
                Cl[row * 128 + j * 16 + (lane & 15)] = *(short*)&hv;
            }
        }
    __syncthreads();
    short* cg = (short*)ctxb;
#pragma unroll
    for (int s = 0; s < 8; ++s) {
        const int c = s * 256 + tid;        // 2048 chunks of 16B
        const int row = c >> 4;
        const int slot = c & 15;
        *(uint4*)&cg[((size_t)(b * T_ + t0 + row)) * D_ + hh * HD_ + slot * 8] =
            *(const uint4*)&Cl[row * 128 + slot * 8];
    }
}

// ---------------------------------------------------------------------------
__global__ __launch_bounds__(256) void frame_summary_kernel(
    const float* __restrict__ cf, float* __restrict__ fs)
{
    const int b = blockIdx.x;
    const int d = blockIdx.y * 256 + threadIdx.x;
    const int t0 = blockIdx.z * 512;
    float s = 0.0f;
    for (int t = t0; t < t0 + 512; ++t)
        s += cf[((size_t)(b * T_ + t)) * D_ + d];
    atomicAdd(&fs[b * D_ + d], s * (1.0f / (float)T_));
}

__global__ __launch_bounds__(256) void mem_summary_kernel(
    const float* __restrict__ em, float* __restrict__ ms)
{
    const int b = blockIdx.x;
    const int d = blockIdx.y * 256 + threadIdx.x;
    float s = 0.0f;
#pragma unroll 4
    for (int n = 0; n < N_; ++n)
        s += em[((size_t)(b * N_ + n)) * D_ + d];
    ms[b * D_ + d] = s * (1.0f / (float)N_);
}

__global__ __launch_bounds__(256) void gate_kernel(
    const float* __restrict__ fs, const float* __restrict__ ms,
    const float* __restrict__ gw, const float* __restrict__ gb,
    float* __restrict__ nm)
{
    const int b = blockIdx.x;
    const int d = blockIdx.y * 256 + threadIdx.x;
    const float* wrow = gw + (size_t)d * D2_;
    const float* f = fs + b * D_;
    const float* mm = ms + b * D_;
    float g = gb[d];
    for (int j = 0; j < D_; ++j) g += f[j] * wrow[j];
    for (int j = 0; j < D_; ++j) g += mm[j] * wrow[D_ + j];
    const float sig = 1.0f / (1.0f + __expf(-g));
    nm[b * D_ + d] = sig * f[d] + (1.0f - sig) * mm[d];
}

__global__ __launch_bounds__(256) void topk_update_kernel(
    const float* __restrict__ S, const float* __restrict__ em,
    const float* __restrict__ nm, float* __restrict__ emo)
{
    const int b = blockIdx.x;
    __shared__ int topi[3];
    const int tid = threadIdx.x;
    if (tid < 64) {
        float sv = S[b * N_ + tid];
#pragma unroll
        for (int k = 0; k < 3; ++k) {
            float v = sv;
            int idx = tid;
#pragma unroll
            for (int off = 32; off; off >>= 1) {
                const float ov = __shfl_xor(v, off);
                const int oi = __shfl_xor(idx, off);
                if (ov > v || (ov == v && oi < idx)) { v = ov; idx = oi; }
            }
            if (tid == 0) topi[k] = idx;
            if (tid == idx) sv = -INFINITY;
        }
    }
    __syncthreads();
    const int i0 = topi[0], i1 = topi[1], i2 = topi[2];
    const float4* emb = (const float4*)(em + (size_t)b * N_ * D_);
    const float4* nmb = (const float4*)(nm + (size_t)b * D_);
    float4* outb = (float4*)(emo + (size_t)b * N_ * D_);
    for (int idx = tid; idx < N_ * D_ / 4; idx += 256) {
        const int n = idx >> 8;
        const int d4 = idx & 255;
        float4 v = emb[idx];
        if (n == i0 || n == i1 || n == i2) {
            const float4 nv = nmb[d4];
            v.x = 0.7f * v.x + 0.3f * nv.x;
            v.y = 0.7f * v.y + 0.3f * nv.y;
            v.z = 0.7f * v.z + 0.3f * nv.z;
            v.w = 0.7f * v.w + 0.3f * nv.w;
        }
        outb[idx] = v;
    }
}

// ---------------------------------------------------------------------------
extern "C" void kernel_launch(void* const* d_in, const int* in_sizes, int n_in,
                              void* d_out, int out_size, void* d_ws, size_t ws_size,
                              hipStream_t stream)
{
    const float* cf  = (const float*)d_in[0];
    const float* em  = (const float*)d_in[1];
    const float* ipw = (const float*)d_in[2];
    const float* ipb = (const float*)d_in[3];
    const float* opw = (const float*)d_in[4];
    const float* opb = (const float*)d_in[5];
    const float* lng = (const float*)d_in[6];
    const float* lnb = (const float*)d_in[7];
    const float* w1  = (const float*)d_in[8];
    const float* b1  = (const float*)d_in[9];
    const float* w2  = (const float*)d_in[10];
    const float* b2  = (const float*)d_in[11];
    const float* gw  = (const float*)d_in[12];
    const float* gb  = (const float*)d_in[13];

    float* x   = (float*)d_out;                  // (B,T,D)
    float* emo = x + (size_t)BT_ * D_;           // (B,N,D)

    // workspace layout (bytes); qb aliases first half of h (q dead before FFN)
    char* w = (char*)d_ws;
    __hip_bfloat16* h    = (__hip_bfloat16*)w;   // 16384x2048 bf16 (64MB)
    __hip_bfloat16* qbuf = (__hip_bfloat16*)w;   // 16384x1024 bf16 (aliases h)
    w += 67108864;
    __hip_bfloat16* actb = (__hip_bfloat16*)w; w += 33554432;  // 16384x1024
    __hip_bfloat16* ipwb = (__hip_bfloat16*)w; w += 6291456;   // 3x1024x1024
    __hip_bfloat16* opwb = (__hip_bfloat16*)w; w += 2097152;   // 1024x1024
    __hip_bfloat16* w1b  = (__hip_bfloat16*)w; w += 12582912;  // 3x2048x1024
    __hip_bfloat16* w2b  = (__hip_bfloat16*)w; w += 12582912;  // 3x1024x2048
    __hip_bfloat16* emb  = (__hip_bfloat16*)w; w += 524288;    // 4x64x1024
    __hip_bfloat16* kvb  = (__hip_bfloat16*)w; w += 1048576;   // 256 x 2048 [k|v]
    __hip_bfloat16* vtb  = (__hip_bfloat16*)w; w += 524288;    // [B,H,128,64]
    float* S  = (float*)w; w += 1024;            // 256 floats
    float* fs = (float*)w; w += 16384;           // 4096
    float* ms = (float*)w; w += 16384;
    float* nm = (float*)w; w += 16384;

    hipMemsetAsync(S, 0, (256 + 4096) * sizeof(float), stream);  // S + fs

    const dim3 blk(256);

    // bf16 copies
    cvt_kernel<<<8192, blk, 0, stream>>>(cf, actb, BT_ * D_);
    cvt_kernel<<<128,  blk, 0, stream>>>(em, emb, B_ * N_ * D_);
    cvt_kernel<<<1536, blk, 0, stream>>>(ipw, ipwb, 3 * D_ * D_);
    cvt_kernel<<<512,  blk, 0, stream>>>(opw, opwb, D_ * D_);
    cvt_kernel<<<3072, blk, 0, stream>>>(w1, w1b, 3 * D2_ * D_);
    cvt_kernel<<<3072, blk, 0, stream>>>(w2, w2b, 3 * D_ * D2_);

    // projections (bf16 MFMA, bf16 out). K+V fused: W rows [D,3D) -> N=2048.
    gemm_bf16_kernel<false, false, true><<<dim3(8, 128), blk, 0, stream>>>(
        actb, ipwb, ipb, nullptr, qbuf, BT_, D_, D_);
    gemm_bf16_kernel<false, false, true><<<dim3(16, 2), blk, 0, stream>>>(
        emb, ipwb + D_ * D_, ipb + D_, nullptr, kvb, B_ * N_, D2_, D_);
    vtrans_kernel<<<B_ * H_, blk, 0, stream>>>(kvb, vtb);

    // attention: ctx (bf16) -> actb, S accumulated
    attn_mfma_kernel<<<dim3(T_ / 128, B_ * H_), blk, 0, stream>>>(
        qbuf, kvb, vtb, actb, S);

    // x = ctx @ out_proj^T + out_proj_b + cf
    gemm_bf16_kernel<false, true, false><<<dim3(8, 128), blk, 0, stream>>>(
        actb, opwb, opb, cf, x, BT_, D_, D_);

    // 3 FFN layers
    for (int i = 0; i < 3; ++i) {
        ln_fused_kernel<<<BT_, blk, 0, stream>>>(
            x, lng + i * D_, lnb + i * D_, actb);
        gemm_bf16_kernel<true, false, true><<<dim3(16, 128), blk, 0, stream>>>(
            actb, w1b + (size_t)i * D2_ * D_, b1 + i * D2_, nullptr, h,
            BT_, D2_, D_);
        gemm_bf16_kernel<false, true, false><<<dim3(8, 128), blk, 0, stream>>>(
            h, w2b + (size_t)i * D_ * D2_, b2 + i * D_, x, x,
            BT_, D_, D2_);
    }

    // summaries + gate + top-k memory update
    frame_summary_kernel<<<dim3(B_, 4, 8), blk, 0, stream>>>(cf, fs);
    mem_summary_kernel<<<dim3(B_, 4), blk, 0, stream>>>(em, ms);
    gate_kernel<<<dim3(B_, 4), blk, 0, stream>>>(fs, ms, gw, gb, nm);
    topk_update_kernel<<<B_, blk, 0, stream>>>(S, em, nm, emo);
}